// Round 11
// baseline (584.924 us; speedup 1.0000x reference)
//
#include <hip/hip_runtime.h>
#include <hip/hip_bf16.h>

#define Bq 2
#define Cc 64
#define Hh 48
#define Ww 48
#define Ll 2304
#define NHh 8
#define DKk 64
#define DVv 128
#define DNn 128
#define NSs 16
#define Rr 4
#define SCH 48
#define SNC 48
#define TT 8      // tokens per block in GEMM-ish kernels

// ---- workspace layout (float offsets) ----
#define OQ    0u                 // (B*8, L, 64) Q bf16 (ushort), pre-scaled by 1/8
#define OK_   2359296u           // (B*8, L, 64) K bf16 (ushort)
#define OV    4718592u           // (free; aliased below)
#define OO    9437184u           // (B, L, 1024) attention out fp32
#define OY2   14450688u
#define OX2   15040512u
#define OXN   15335424u
#define OVT   15630336u          // (B*8, 128, L) V^T bf16 (ushort)
#define WS_NEED_FLOATS (OVT + 4718592u)
// aliases (lifetimes: q,k,vt dead after k_attn; o dead after k_oprojxz)
#define ODT2  OQ                 // (B*4, L, 128) dt, l-major
#define OYS2  OK_                // (B*4, L, 128) scan y, l-major
#define OX1P  OV                 // (B,L,128)
#define OZ    (OV + 589824u)     // (B,L,128)
#define OX1S  (OV + 1179648u)    // (B,L,128)
#define OBS2  (OV + 1769472u)    // (B*4, L, 16)
#define OCS2  (OV + 2064384u)    // (B*4, L, 16)
#define OCSA  (OV + 2359296u)    // (B*4, SNC, 128, 16)
#define OCSB  (OV + 3145728u)    // (B*4, SNC, 128, 16)
#define OHST  (OV + 3932160u)    // (B*4, SNC, 128, 16)
#define OH1A  OO                 // (B,L,256)
#define OH1B  (OO + 1179648u)    // (B,L,256)

typedef short short8v __attribute__((ext_vector_type(8)));
typedef short short4v __attribute__((ext_vector_type(4)));
typedef float f32x4 __attribute__((ext_vector_type(4)));
typedef unsigned short ushort_t;

__device__ __forceinline__ float geluf(float x) {
  return 0.5f * x * (1.0f + erff(x * 0.70710678118654752f));
}
__device__ __forceinline__ float siluf(float x) {
  return x / (1.0f + __expf(-x));
}
__device__ __forceinline__ float softplusf(float x) {
  return fmaxf(x, 0.0f) + log1pf(__expf(-fabsf(x)));
}
__device__ __forceinline__ int spmap(int k, int l) {
  if (k == 0) return l;
  if (k == 1) return (l % 48) * 48 + l / 48;
  if (k == 2) return 2303 - l;
  int l2 = 2303 - l; return (l2 % 48) * 48 + l2 / 48;
}
__device__ __forceinline__ short f2bf(float f) {
  unsigned u = __float_as_uint(f);
  unsigned r = (u + 0x7FFFu + ((u >> 16) & 1u)) >> 16;
  return (short)r;
}

__global__ void k_code(float* out) { if (threadIdx.x == 0) out[0] = 25000.f; }

// ============ 1. QKV projection, 8 tokens/block; V written transposed bf16 ============
__global__ __launch_bounds__(256) void k_qkv(const float* __restrict__ enc,
    const float* __restrict__ wq, const float* __restrict__ wk,
    const float* __restrict__ wv, float* __restrict__ ws) {
  int l0 = blockIdx.x * TT; int b = blockIdx.y;
  int t = threadIdx.x;
  __shared__ float xs[64][12];   // [c][token]
  {
    int idx = t, c = idx >> 3, i = idx & 7;
    xs[c][i] = enc[(size_t)b * Cc * Ll + (size_t)c * Ll + l0 + i];
    idx = t + 256; c = idx >> 3; i = idx & 7;
    xs[c][i] = enc[(size_t)b * Cc * Ll + (size_t)c * Ll + l0 + i];
  }
  __syncthreads();
  ushort_t* qb = (ushort_t*)(ws + OQ);
  ushort_t* kb = (ushort_t*)(ws + OK_);
  ushort_t* vtb = (ushort_t*)(ws + OVT);
#pragma unroll
  for (int g = 0; g < 6; ++g) {
    int j = t + g * 256;
    float acc[TT];
#pragma unroll
    for (int i = 0; i < TT; ++i) acc[i] = 0.f;
    const float* wp; int col, stride;
    if (j < 512) { wp = wq + j; stride = 512; col = j; }
    else if (j < 1024) { wp = wk + (j - 512); stride = 512; col = j - 512; }
    else { wp = wv + (j - 1024); stride = 1024; col = j - 1024; }
    for (int c = 0; c < 64; ++c) {
      float w = wp[(size_t)c * stride];
      const float4* xc = (const float4*)&xs[c][0];
      float4 x0 = xc[0], x1 = xc[1];
      acc[0] += x0.x * w; acc[1] += x0.y * w;
      acc[2] += x0.z * w; acc[3] += x0.w * w;
      acc[4] += x1.x * w; acc[5] += x1.y * w;
      acc[6] += x1.z * w; acc[7] += x1.w * w;
    }
    if (j < 512) {
#pragma unroll
      for (int i = 0; i < TT; ++i)
        qb[((size_t)(b * 8 + (col >> 6)) * Ll + l0 + i) * 64 + (col & 63)] =
            (ushort_t)f2bf(acc[i] * 0.125f);
    } else if (j < 1024) {
#pragma unroll
      for (int i = 0; i < TT; ++i)
        kb[((size_t)(b * 8 + (col >> 6)) * Ll + l0 + i) * 64 + (col & 63)] =
            (ushort_t)f2bf(acc[i]);
    } else {
      int bh2 = b * 8 + (col >> 7), dv = col & 127;
      short tmp[8];
#pragma unroll
      for (int i = 0; i < TT; ++i) tmp[i] = f2bf(acc[i]);
      *(short8v*)(vtb + ((size_t)bh2 * 128 + dv) * Ll + l0) = *(short8v*)tmp;
    }
  }
}

// ============ 2. flash attention (bf16 MFMA, fixed-max softmax, no per-iter shuffles) ============
#define NKT 36
#define LSK 72
__global__ __launch_bounds__(256) void k_attn(const float* __restrict__ snr,
                                              float* __restrict__ ws) {
  int bh = blockIdx.y; int b = bh >> 3; int hd = bh & 7;
  int q0 = blockIdx.x * 64;
  int t = threadIdx.x;
  int w = t >> 6, lane = t & 63;
  int m16 = lane & 15, quad = lane >> 4;

  __shared__ __align__(16) ushort_t Ks[64 * LSK];
  __shared__ __align__(16) ushort_t Vs[128 * LSK];
  __shared__ __align__(16) ushort_t Ps[4 * 16 * LSK];
  __shared__ float sfac_s[64];
  __shared__ float lsc[4][16];

  const ushort_t* qbf = (const ushort_t*)(ws + OQ) + (size_t)bh * Ll * 64;
  const ushort_t* kbf = (const ushort_t*)(ws + OK_) + (size_t)bh * Ll * 64;
  const ushort_t* vtb = (const ushort_t*)(ws + OVT) + (size_t)bh * 128 * Ll;

  short8v qa[2];
  {
    const ushort_t* qrp = qbf + (size_t)(q0 + w * 16 + m16) * 64 + quad * 8;
    qa[0] = *(const short8v*)qrp;
    qa[1] = *(const short8v*)(qrp + 32);
  }
  int sk_key = t >> 2, sk_d0 = (t & 3) * 16;
  int sv_dv = t >> 1, sv_k0 = (t & 1) * 32;

  short8v kreg[2], vreg[4];
  float snr_reg = 0.f;
  {
    const ushort_t* ksrc = kbf + (size_t)sk_key * 64 + sk_d0;
    kreg[0] = *(const short8v*)ksrc;
    kreg[1] = *(const short8v*)(ksrc + 8);
    const ushort_t* vsrc = vtb + (size_t)sv_dv * Ll + sv_k0;
#pragma unroll
    for (int i = 0; i < 4; ++i) vreg[i] = *(const short8v*)(vsrc + i * 8);
    if (t < 64) snr_reg = snr[b * Ll + t];
  }

  f32x4 oacc[8];
#pragma unroll
  for (int i = 0; i < 8; ++i) oacc[i] = (f32x4)0.f;
  float l_r[4] = {0.f, 0.f, 0.f, 0.f};

  for (int kt = 0; kt < NKT; ++kt) {
    __syncthreads();
    *(short8v*)&Ks[sk_key * LSK + sk_d0] = kreg[0];
    *(short8v*)&Ks[sk_key * LSK + sk_d0 + 8] = kreg[1];
#pragma unroll
    for (int i = 0; i < 4; ++i)
      *(short8v*)&Vs[sv_dv * LSK + sv_k0 + i * 8] = vreg[i];
    if (t < 64) sfac_s[t] = snr_reg + 1e-4f;
    __syncthreads();
    if (kt + 1 < NKT) {
      int k0n = (kt + 1) * 64;
      const ushort_t* ksrc = kbf + (size_t)(k0n + sk_key) * 64 + sk_d0;
      kreg[0] = *(const short8v*)ksrc;
      kreg[1] = *(const short8v*)(ksrc + 8);
      const ushort_t* vsrc = vtb + (size_t)sv_dv * Ll + k0n + sv_k0;
#pragma unroll
      for (int i = 0; i < 4; ++i) vreg[i] = *(const short8v*)(vsrc + i * 8);
      if (t < 64) snr_reg = snr[b * Ll + k0n + t];
    }

    // QK^T: 4 N-tiles of 16 keys (Q pre-scaled by 1/8)
    f32x4 sac[4];
#pragma unroll
    for (int n = 0; n < 4; ++n) {
      int key = n * 16 + m16;
      short8v kb0 = *(const short8v*)&Ks[key * LSK + quad * 8];
      short8v kb1 = *(const short8v*)&Ks[key * LSK + 32 + quad * 8];
      f32x4 acc = (f32x4)0.f;
      acc = __builtin_amdgcn_mfma_f32_16x16x32_bf16(qa[0], kb0, acc, 0, 0, 0);
      acc = __builtin_amdgcn_mfma_f32_16x16x32_bf16(qa[1], kb1, acc, 0, 0, 0);
      sac[n] = acc;
    }
    // fixed-max softmax: p = (snr+1e-4) * exp(qk); l = plain sum (deferred reduce)
    float sf[4];
#pragma unroll
    for (int n = 0; n < 4; ++n) sf[n] = sfac_s[n * 16 + m16];
    ushort_t* pw = &Ps[w * 16 * LSK];
#pragma unroll
    for (int r = 0; r < 4; ++r) {
#pragma unroll
      for (int n = 0; n < 4; ++n) {
        float p = __expf(sac[n][r]) * sf[n];
        l_r[r] += p;
        pw[(quad * 4 + r) * LSK + n * 16 + m16] = (ushort_t)f2bf(p);
      }
    }
    short8v pb0 = *(const short8v*)&pw[m16 * LSK + quad * 8];
    short8v pb1 = *(const short8v*)&pw[m16 * LSK + 32 + quad * 8];
#pragma unroll
    for (int dt_ = 0; dt_ < 8; ++dt_) {
      const ushort_t* vrow = &Vs[(dt_ * 16 + m16) * LSK];
      short8v va0 = *(const short8v*)&vrow[quad * 8];
      short8v va1 = *(const short8v*)&vrow[32 + quad * 8];
      f32x4 o = oacc[dt_];
      o = __builtin_amdgcn_mfma_f32_16x16x32_bf16(va0, pb0, o, 0, 0, 0);
      o = __builtin_amdgcn_mfma_f32_16x16x32_bf16(va1, pb1, o, 0, 0, 0);
      oacc[dt_] = o;
    }
  }
  // one-time row-sum reduction over the 16 key-lanes
#pragma unroll
  for (int r = 0; r < 4; ++r) {
    float lv = l_r[r];
    lv += __shfl_xor(lv, 1, 64);
    lv += __shfl_xor(lv, 2, 64);
    lv += __shfl_xor(lv, 4, 64);
    lv += __shfl_xor(lv, 8, 64);
    l_r[r] = lv;
  }
  if (m16 == 0) {
#pragma unroll
    for (int r = 0; r < 4; ++r) lsc[w][quad * 4 + r] = l_r[r];
  }
  float linv = 1.f / lsc[w][m16];
  float* op = ws + OO + ((size_t)(b * Ll + q0 + w * 16 + m16)) * 1024 + hd * 128;
#pragma unroll
  for (int dt_ = 0; dt_ < 8; ++dt_) {
#pragma unroll
    for (int r = 0; r < 4; ++r) {
      op[dt_ * 16 + quad * 4 + r] = oacc[dt_][r] * linv;
    }
  }
}

// ============ 3+4. o@fc + residual + LN + xz, 8 tokens/block ============
__global__ __launch_bounds__(256) void k_oprojxz(const float* __restrict__ enc,
    const float* __restrict__ fc, const float* __restrict__ lnw,
    const float* __restrict__ lnb, const float* __restrict__ ssin,
    float* __restrict__ ws) {
  int l0 = blockIdx.x * TT, b = blockIdx.y, t = threadIdx.x;
  __shared__ float orow[1024][9];
  __shared__ float part[4][TT][64];
  __shared__ float xh_s[64][9];
  const float* op = ws + OO + ((size_t)(b * Ll + l0)) * 1024;
#pragma unroll
  for (int k = 0; k < 4; ++k) {
    int c = t + k * 256;
#pragma unroll
    for (int i = 0; i < TT; ++i) orow[c][i] = op[(size_t)i * 1024 + c];
  }
  __syncthreads();
  int col = t & 63, seg = t >> 6;
  {
    float acc[TT];
#pragma unroll
    for (int i = 0; i < TT; ++i) acc[i] = 0.f;
    const float* fcs = fc + (size_t)(seg * 256) * 64 + col;
    for (int c = 0; c < 256; ++c) {
      float w = fcs[(size_t)c * 64];
      const float* orc = &orow[seg * 256 + c][0];
#pragma unroll
      for (int i = 0; i < TT; ++i) acc[i] += orc[i] * w;
    }
#pragma unroll
    for (int i = 0; i < TT; ++i) part[seg][i][col] = acc[i];
  }
  __syncthreads();
  if (t < 64) {
    float lw = lnw[t], lb = lnb[t];
#pragma unroll
    for (int i = 0; i < TT; ++i) {
      float a = part[0][i][t] + part[1][i][t] + part[2][i][t] + part[3][i][t];
      a += enc[(size_t)b * Cc * Ll + (size_t)t * Ll + l0 + i];
      float s = a;
#pragma unroll
      for (int o = 32; o >= 1; o >>= 1) s += __shfl_xor(s, o, 64);
      float m = s * (1.f / 64.f);
      float dd = a - m;
      float vs = dd * dd;
#pragma unroll
      for (int o = 32; o >= 1; o >>= 1) vs += __shfl_xor(vs, o, 64);
      xh_s[t][i] = dd * rsqrtf(vs * (1.f / 64.f) + 1e-5f) * lw + lb;
    }
  }
  __syncthreads();
  {
    float acc2[TT];
#pragma unroll
    for (int i = 0; i < TT; ++i) acc2[i] = 0.f;
    for (int c = 0; c < 64; ++c) {
      float w = ssin[c * 256 + t];
      const float* xc = &xh_s[c][0];
#pragma unroll
      for (int i = 0; i < TT; ++i) acc2[i] += xc[i] * w;
    }
    if (t < 128) {
#pragma unroll
      for (int i = 0; i < TT; ++i)
        ws[OX1P + ((size_t)(b * Ll + l0 + i)) * 128 + t] = acc2[i];
    } else {
#pragma unroll
      for (int i = 0; i < TT; ++i)
        ws[OZ + ((size_t)(b * Ll + l0 + i)) * 128 + (t - 128)] = acc2[i];
    }
  }
}

// ============ 5. depthwise conv3x3 + bias + silu ============
__global__ __launch_bounds__(128) void k_conv(const float* __restrict__ cw,
    const float* __restrict__ cb, float* __restrict__ ws) {
  int l = blockIdx.x, b = blockIdx.y, d = threadIdx.x;
  int h = l / 48, w = l % 48;
  float acc = cb[d];
#pragma unroll
  for (int kh = 0; kh < 3; ++kh) {
    int hh = h + kh - 1;
    if (hh < 0 || hh >= 48) continue;
#pragma unroll
    for (int kw = 0; kw < 3; ++kw) {
      int wx = w + kw - 1;
      if (wx < 0 || wx >= 48) continue;
      acc += ws[OX1P + ((size_t)b * Ll + hh * 48 + wx) * 128 + d] *
             cw[d * 9 + kh * 3 + kw];
    }
  }
  ws[OX1S + ((size_t)b * Ll + l) * 128 + d] = siluf(acc);
}

// ============ 6. x_dbl projections, 8 tokens/block ============
__global__ __launch_bounds__(128) void k_xdbl(const float* __restrict__ xw,
    const float* __restrict__ dtw, const float* __restrict__ dtb,
    float* __restrict__ ws) {
  int l0 = blockIdx.x * TT;
  int by = blockIdx.y; int b = by >> 2; int k = by & 3;
  int t = threadIdx.x;
  __shared__ float xv[128][9];
  __shared__ float pr[36][TT];
#pragma unroll
  for (int i = 0; i < TT; ++i) {
    int sp = spmap(k, l0 + i);
    xv[t][i] = ws[OX1S + ((size_t)(b * Ll) + sp) * 128 + t];
  }
  __syncthreads();
  if (t < 36) {
    float s[TT];
#pragma unroll
    for (int i = 0; i < TT; ++i) s[i] = 0.f;
    const float* wp = xw + (size_t)(k * 36 + t) * 128;
    for (int d = 0; d < 128; ++d) {
      float w = wp[d];
      const float* xc = &xv[d][0];
#pragma unroll
      for (int i = 0; i < TT; ++i) s[i] += xc[i] * w;
    }
#pragma unroll
    for (int i = 0; i < TT; ++i) pr[t][i] = s[i];
  }
  __syncthreads();
  {
    int d = t;
    const float* wp = dtw + (size_t)(k * 128 + d) * 4;
    float w0 = wp[0], w1 = wp[1], w2 = wp[2], w3 = wp[3];
    float bb = dtb[k * 128 + d];
#pragma unroll
    for (int i = 0; i < TT; ++i) {
      float v = pr[0][i] * w0 + pr[1][i] * w1 + pr[2][i] * w2 + pr[3][i] * w3 + bb;
      ws[ODT2 + ((size_t)(by * Ll + l0 + i)) * 128 + d] = softplusf(v);
    }
  }
  if (t < 16) {
#pragma unroll
    for (int i = 0; i < TT; ++i)
      ws[OBS2 + ((size_t)(by * Ll + l0 + i)) * 16 + t] = pr[4 + t][i];
  } else if (t < 32) {
#pragma unroll
    for (int i = 0; i < TT; ++i)
      ws[OCS2 + ((size_t)(by * Ll + l0 + i)) * 16 + (t - 16)] = pr[20 + (t - 16)][i];
  }
}

// ============ 7a. scan phase A ============
__global__ __launch_bounds__(256) void k_scanA(const float* __restrict__ alog,
                                               float* __restrict__ ws) {
  int c = blockIdx.x;
  int bk = blockIdx.y;
  int b = bk >> 2, k = bk & 3;
  int t = threadIdx.x;
  int n = t & 15, dg = t >> 4;
  __shared__ float dt_s[128], x_s[128], Bs_s[16];
  float A_r[8], ap[8], bc[8];
#pragma unroll
  for (int i = 0; i < 8; ++i) {
    int d = dg * 8 + i;
    A_r[i] = -__expf(alog[(size_t)((k * 128 + d) * 16) + n]);
    ap[i] = 1.f; bc[i] = 0.f;
  }
  const float* dtp = ws + ODT2 + ((size_t)bk * Ll) * 128;
  const float* bsp = ws + OBS2 + ((size_t)bk * Ll) * 16;
  const float* xb = ws + OX1S + (size_t)b * Ll * 128;
  for (int ll = 0; ll < SCH; ++ll) {
    int l = c * SCH + ll;
    int sp = spmap(k, l);
    if (t < 128) dt_s[t] = dtp[(size_t)l * 128 + t];
    else x_s[t - 128] = xb[(size_t)sp * 128 + (t - 128)];
    if (t < 16) Bs_s[t] = bsp[(size_t)l * 16 + t];
    __syncthreads();
    float Bv = Bs_s[n];
#pragma unroll
    for (int i = 0; i < 8; ++i) {
      int d = dg * 8 + i;
      float dtv = dt_s[d];
      float a = __expf(dtv * A_r[i]);
      bc[i] = bc[i] * a + dtv * x_s[d] * Bv;
      ap[i] *= a;
    }
    __syncthreads();
  }
  float* csa = ws + OCSA + ((size_t)(bk * SNC + c) * 128) * 16;
  float* csb = ws + OCSB + ((size_t)(bk * SNC + c) * 128) * 16;
#pragma unroll
  for (int i = 0; i < 8; ++i) {
    int d = dg * 8 + i;
    csa[d * 16 + n] = ap[i];
    csb[d * 16 + n] = bc[i];
  }
}

// ============ 7b. scan phase B ============
__global__ __launch_bounds__(256) void k_scanB(float* __restrict__ ws) {
  int g = blockIdx.x * 256 + threadIdx.x;
  int bk = g >> 11;
  int dn = g & 2047;
  const float* csa = ws + OCSA;
  const float* csb = ws + OCSB;
  float* hst = ws + OHST;
  float h = 0.f;
  for (int c = 0; c < SNC; ++c) {
    size_t idx = (size_t)(bk * SNC + c) * 2048 + dn;
    hst[idx] = h;
    h = csa[idx] * h + csb[idx];
  }
}

// ============ 7c. scan phase C ============
__global__ __launch_bounds__(256) void k_scanC(const float* __restrict__ alog,
    const float* __restrict__ Dp, float* __restrict__ ws) {
  int c = blockIdx.x, bk = blockIdx.y;
  int b = bk >> 2, k = bk & 3;
  int t = threadIdx.x;
  int n = t & 15, dg = t >> 4;
  __shared__ float dt_s[128], x_s[128], Bs_s[16], Cs_s[16];
  float A_r[8], h[8], Dv[8];
#pragma unroll
  for (int i = 0; i < 8; ++i) {
    int d = dg * 8 + i;
    A_r[i] = -__expf(alog[(size_t)((k * 128 + d) * 16) + n]);
    h[i] = ws[OHST + ((size_t)(bk * SNC + c) * 128 + d) * 16 + n];
    Dv[i] = Dp[k * 128 + d];
  }
  const float* dtp = ws + ODT2 + ((size_t)bk * Ll) * 128;
  const float* bsp = ws + OBS2 + ((size_t)bk * Ll) * 16;
  const float* csp = ws + OCS2 + ((size_t)bk * Ll) * 16;
  const float* xb = ws + OX1S + (size_t)b * Ll * 128;
  float* yp = ws + OYS2 + ((size_t)bk * Ll) * 128;
  for (int ll = 0; ll < SCH; ++ll) {
    int l = c * SCH + ll;
    int sp = spmap(k, l);
    if (t < 128) dt_s[t] = dtp[(size_t)l * 128 + t];
    else x_s[t - 128] = xb[(size_t)sp * 128 + (t - 128)];
    if (t < 16) Bs_s[t] = bsp[(size_t)l * 16 + t];
    else if (t < 32) Cs_s[t - 16] = csp[(size_t)l * 16 + (t - 16)];
    __syncthreads();
    float Bv = Bs_s[n], Cv = Cs_s[n];
    float yacc[8];
#pragma unroll
    for (int i = 0; i < 8; ++i) {
      int d = dg * 8 + i;
      float dtv = dt_s[d];
      float a = __expf(dtv * A_r[i]);
      h[i] = h[i] * a + dtv * x_s[d] * Bv;
      yacc[i] = h[i] * Cv;
    }
#pragma unroll
    for (int i = 0; i < 8; ++i) {
      float yv = yacc[i];
      yv += __shfl_xor(yv, 1, 64);
      yv += __shfl_xor(yv, 2, 64);
      yv += __shfl_xor(yv, 4, 64);
      yv += __shfl_xor(yv, 8, 64);
      yacc[i] = yv;
    }
    if (n == 0) {
#pragma unroll
      for (int i = 0; i < 8; ++i) {
        int d = dg * 8 + i;
        yp[(size_t)l * 128 + d] = yacc[i] + Dv[i] * x_s[d];
      }
    }
    __syncthreads();
  }
}

// ============ 8. combine dirs + LN + gate ============
__global__ __launch_bounds__(128) void k_comb(const float* __restrict__ nw,
    const float* __restrict__ nb, const float* __restrict__ snr,
    float* __restrict__ ws) {
  int l = blockIdx.x, b = blockIdx.y, d = threadIdx.x;
  int h = l / 48, w = l % 48;
  int lT = w * 48 + h;
  const float* ysb = ws + OYS2;
  float v = ysb[((size_t)(b * 4 + 0) * Ll + l) * 128 + d] +
            ysb[((size_t)(b * 4 + 2) * Ll + (2303 - l)) * 128 + d] +
            ysb[((size_t)(b * 4 + 1) * Ll + lT) * 128 + d] +
            ysb[((size_t)(b * 4 + 3) * Ll + (2303 - lT)) * 128 + d];
  __shared__ float red[4];
  int lane = d & 63, wid = d >> 6;
  float s = v;
#pragma unroll
  for (int o = 32; o >= 1; o >>= 1) s += __shfl_xor(s, o, 64);
  if (lane == 0) red[wid] = s;
  __syncthreads();
  float m = (red[0] + red[1]) * (1.f / 128.f);
  float dv_ = v - m;
  float q = dv_ * dv_;
#pragma unroll
  for (int o = 32; o >= 1; o >>= 1) q += __shfl_xor(q, o, 64);
  if (lane == 0) red[wid + 2] = q;
  __syncthreads();
  float var = (red[2] + red[3]) * (1.f / 128.f);
  float y = dv_ * rsqrtf(var + 1e-5f) * nw[d] + nb[d];
  float zv = ws[OZ + ((size_t)b * Ll + l) * 128 + d];
  y *= siluf(zv);
  y *= snr[b * Ll + l];
  ws[OY2 + ((size_t)b * Ll + l) * 128 + d] = y;
}

// ============ 9+10. x2 + LN + FFN conv1 + gelu, 8 tokens/block ============
__global__ __launch_bounds__(256) void k_outffn1(const float* __restrict__ enc,
    const float* __restrict__ ow, const float* __restrict__ lw,
    const float* __restrict__ lb, const float* __restrict__ w1,
    float* __restrict__ ws) {
  int l0 = blockIdx.x * TT, b = blockIdx.y, t = threadIdx.x;
  __shared__ float yr[128][9];
  __shared__ float part[2][TT][64];
  __shared__ float xn_s[64][9];
  const float* yp = ws + OY2 + ((size_t)(b * Ll + l0)) * 128;
  if (t < 128) {
#pragma unroll
    for (int i = 0; i < TT; ++i) yr[t][i] = yp[(size_t)i * 128 + t];
  }
  __syncthreads();
  if (t < 128) {
    int col = t & 63, seg = t >> 6;
    float acc[TT];
#pragma unroll
    for (int i = 0; i < TT; ++i) acc[i] = 0.f;
    const float* ows = ow + (size_t)(seg * 64) * 64 + col;
    for (int c = 0; c < 64; ++c) {
      float w = ows[c * 64];
      const float* yc = &yr[seg * 64 + c][0];
#pragma unroll
      for (int i = 0; i < TT; ++i) acc[i] += yc[i] * w;
    }
#pragma unroll
    for (int i = 0; i < TT; ++i) part[seg][i][col] = acc[i];
  }
  __syncthreads();
  if (t < 64) {
    float lwv = lw[t], lbv = lb[t];
#pragma unroll
    for (int i = 0; i < TT; ++i) {
      float a = part[0][i][t] + part[1][i][t];
      a += enc[(size_t)b * Cc * Ll + (size_t)t * Ll + l0 + i];
      ws[OX2 + ((size_t)(b * Ll + l0 + i)) * 64 + t] = a;
      float s = a;
#pragma unroll
      for (int o = 32; o >= 1; o >>= 1) s += __shfl_xor(s, o, 64);
      float m = s * (1.f / 64.f);
      float dd2 = a - m;
      float vs = dd2 * dd2;
#pragma unroll
      for (int o = 32; o >= 1; o >>= 1) vs += __shfl_xor(vs, o, 64);
      xn_s[t][i] = dd2 * rsqrtf(vs * (1.f / 64.f) + 1e-5f) * lwv + lbv;
    }
  }
  __syncthreads();
  {
    float acc2[TT];
#pragma unroll
    for (int i = 0; i < TT; ++i) acc2[i] = 0.f;
    const float* wp = w1 + (size_t)t * 64;
    for (int c = 0; c < 64; ++c) {
      float w = wp[c];
      const float* xc = &xn_s[c][0];
#pragma unroll
      for (int i = 0; i < TT; ++i) acc2[i] += xc[i] * w;
    }
#pragma unroll
    for (int i = 0; i < TT; ++i)
      ws[OH1A + ((size_t)(b * Ll + l0 + i)) * 256 + t] = geluf(acc2[i]);
  }
}

// ============ 11. FFN depthwise 3x3 + gelu ============
__global__ __launch_bounds__(256) void k_ffndw(const float* __restrict__ dww,
                                               float* __restrict__ ws) {
  int l = blockIdx.x, b = blockIdx.y, mch = threadIdx.x;
  int h = l / 48, w = l % 48;
  float acc = 0.f;
#pragma unroll
  for (int kh = 0; kh < 3; ++kh) {
    int hh = h + kh - 1;
    if (hh < 0 || hh >= 48) continue;
#pragma unroll
    for (int kw = 0; kw < 3; ++kw) {
      int wx = w + kw - 1;
      if (wx < 0 || wx >= 48) continue;
      acc += ws[OH1A + ((size_t)b * Ll + hh * 48 + wx) * 256 + mch] *
             dww[mch * 9 + kh * 3 + kw];
    }
  }
  ws[OH1B + ((size_t)b * Ll + l) * 256 + mch] = geluf(acc);
}

// ============ 12. FFN conv2 1x1 + residual + transposed out, 8 tokens/block ============
__global__ __launch_bounds__(256) void k_ffn2(const float* __restrict__ w2,
                                              float* __restrict__ ws,
                                              float* __restrict__ out) {
  int l0 = blockIdx.x * TT, b = blockIdx.y, t = threadIdx.x;
  __shared__ float hr[256][9];
  __shared__ float part[4][TT][64];
  const float* hp = ws + OH1B + ((size_t)(b * Ll + l0)) * 256;
#pragma unroll
  for (int i = 0; i < TT; ++i) hr[t][i] = hp[(size_t)i * 256 + t];
  __syncthreads();
  int col = t & 63, seg = t >> 6;
  {
    float acc[TT];
#pragma unroll
    for (int i = 0; i < TT; ++i) acc[i] = 0.f;
    const float* wp = w2 + (size_t)col * 256 + seg * 64;
    for (int c = 0; c < 64; ++c) {
      float w = wp[c];
      const float* hc = &hr[seg * 64 + c][0];
#pragma unroll
      for (int i = 0; i < TT; ++i) acc[i] += hc[i] * w;
    }
#pragma unroll
    for (int i = 0; i < TT; ++i) part[seg][i][col] = acc[i];
  }
  __syncthreads();
  if (t < 64) {
    float av[TT];
#pragma unroll
    for (int i = 0; i < TT; ++i) {
      float a = part[0][i][t] + part[1][i][t] + part[2][i][t] + part[3][i][t];
      av[i] = a + ws[OX2 + ((size_t)(b * Ll + l0 + i)) * 64 + t];
    }
    float* opx = out + ((size_t)(b * 64 + t)) * 2304 + l0;
    *(float4*)opx = make_float4(av[0], av[1], av[2], av[3]);
    *((float4*)opx + 1) = make_float4(av[4], av[5], av[6], av[7]);
  }
}

extern "C" void kernel_launch(void* const* d_in, const int* in_sizes, int n_in,
                              void* d_out, int out_size, void* d_ws, size_t ws_size,
                              hipStream_t stream) {
  (void)in_sizes; (void)n_in; (void)out_size;
  const float* enc  = (const float*)d_in[0];
  const float* snr  = (const float*)d_in[1];
  const float* wq   = (const float*)d_in[2];
  const float* wk   = (const float*)d_in[3];
  const float* wv   = (const float*)d_in[4];
  const float* fc   = (const float*)d_in[5];
  const float* alnw = (const float*)d_in[6];
  const float* alnb = (const float*)d_in[7];
  const float* ssin = (const float*)d_in[8];
  const float* cw   = (const float*)d_in[9];
  const float* cb   = (const float*)d_in[10];
  const float* xw   = (const float*)d_in[11];
  const float* dtw  = (const float*)d_in[12];
  const float* dtb  = (const float*)d_in[13];
  const float* alog = (const float*)d_in[14];
  const float* Dp   = (const float*)d_in[15];
  const float* nw   = (const float*)d_in[16];
  const float* nb   = (const float*)d_in[17];
  const float* ow   = (const float*)d_in[18];
  const float* flnw = (const float*)d_in[19];
  const float* flnb = (const float*)d_in[20];
  const float* w1   = (const float*)d_in[21];
  const float* dww  = (const float*)d_in[22];
  const float* w2   = (const float*)d_in[23];
  float* ws = (float*)d_ws;
  float* out = (float*)d_out;

  if (ws_size < (size_t)WS_NEED_FLOATS * 4) {
    hipLaunchKernelGGL(k_code, dim3(1), dim3(64), 0, stream, out);
    return;
  }

  hipLaunchKernelGGL(k_qkv, dim3(Ll / TT, Bq), dim3(256), 0, stream, enc, wq, wk, wv, ws);
  hipLaunchKernelGGL(k_attn, dim3(Ll / 64, Bq * NHh), dim3(256), 0, stream, snr, ws);
  hipLaunchKernelGGL(k_oprojxz, dim3(Ll / TT, Bq), dim3(256), 0, stream, enc, fc, alnw, alnb, ssin, ws);
  hipLaunchKernelGGL(k_conv, dim3(Ll, Bq), dim3(128), 0, stream, cw, cb, ws);
  hipLaunchKernelGGL(k_xdbl, dim3(Ll / TT, Bq * 4), dim3(128), 0, stream, xw, dtw, dtb, ws);
  hipLaunchKernelGGL(k_scanA, dim3(SNC, Bq * 4), dim3(256), 0, stream, alog, ws);
  hipLaunchKernelGGL(k_scanB, dim3(64), dim3(256), 0, stream, ws);
  hipLaunchKernelGGL(k_scanC, dim3(SNC, Bq * 4), dim3(256), 0, stream, alog, Dp, ws);
  hipLaunchKernelGGL(k_comb, dim3(Ll, Bq), dim3(128), 0, stream, nw, nb, snr, ws);
  hipLaunchKernelGGL(k_outffn1, dim3(Ll / TT, Bq), dim3(256), 0, stream, enc, ow, flnw, flnb, w1, ws);
  hipLaunchKernelGGL(k_ffndw, dim3(Ll, Bq), dim3(256), 0, stream, dww, ws);
  hipLaunchKernelGGL(k_ffn2, dim3(Ll / TT, Bq), dim3(256), 0, stream, w2, ws, out);
}

// Round 12
// 461.231 us; speedup vs baseline: 1.2682x; 1.2682x over previous
//
#include <hip/hip_runtime.h>
#include <hip/hip_bf16.h>

#define Bq 2
#define Cc 64
#define Hh 48
#define Ww 48
#define Ll 2304
#define NHh 8
#define DKk 64
#define DVv 128
#define DNn 128
#define NSs 16
#define Rr 4
#define SCH 48
#define SNC 48
#define TT 8      // tokens per block in GEMM-ish kernels

// ---- workspace layout (float offsets) ----
#define OQ    0u                 // (B*8, L, 64) Q bf16 (ushort), pre-scaled by 1/8
#define OK_   2359296u           // (B*8, L, 64) K bf16 (ushort)
#define OV    4718592u           // (B*8, L, 128) V fp32
#define OO    9437184u           // (B, L, 1024) attention out fp32
#define OY2   14450688u
#define OX2   15040512u
#define OXN   15335424u
#define OVT   15630336u          // (B*8, 128, L) V^T bf16 (ushort)
#define WS_NEED_FLOATS (OVT + 4718592u)
// aliases (lifetimes: q,k,v,vt dead after k_attn; o dead after k_oprojxz)
#define ODT2  OQ                 // (B*4, L, 128) dt, l-major
#define OYS2  OK_                // (B*4, L, 128) scan y, l-major
#define OX1P  OV                 // (B,L,128)
#define OZ    (OV + 589824u)     // (B,L,128)
#define OX1S  (OV + 1179648u)    // (B,L,128)
#define OBS2  (OV + 1769472u)    // (B*4, L, 16)
#define OCS2  (OV + 2064384u)    // (B*4, L, 16)
#define OCSA  (OV + 2359296u)    // (B*4, SNC, 128, 16)
#define OCSB  (OV + 3145728u)    // (B*4, SNC, 128, 16)
#define OHST  (OV + 3932160u)    // (B*4, SNC, 128, 16)
#define OH1A  OO                 // (B,L,256)
#define OH1B  (OO + 1179648u)    // (B,L,256)

typedef short short8v __attribute__((ext_vector_type(8)));
typedef short short4v __attribute__((ext_vector_type(4)));
typedef float f32x4 __attribute__((ext_vector_type(4)));
typedef unsigned short ushort_t;

__device__ __forceinline__ float geluf(float x) {
  return 0.5f * x * (1.0f + erff(x * 0.70710678118654752f));
}
__device__ __forceinline__ float siluf(float x) {
  return x / (1.0f + __expf(-x));
}
__device__ __forceinline__ float softplusf(float x) {
  return fmaxf(x, 0.0f) + log1pf(__expf(-fabsf(x)));
}
__device__ __forceinline__ int spmap(int k, int l) {
  if (k == 0) return l;
  if (k == 1) return (l % 48) * 48 + l / 48;
  if (k == 2) return 2303 - l;
  int l2 = 2303 - l; return (l2 % 48) * 48 + l2 / 48;
}
__device__ __forceinline__ short f2bf(float f) {
  unsigned u = __float_as_uint(f);
  unsigned r = (u + 0x7FFFu + ((u >> 16) & 1u)) >> 16;
  return (short)r;
}

__global__ void k_code(float* out) { if (threadIdx.x == 0) out[0] = 25000.f; }

// ============ 1. QKV projection, 8 tokens/block (V fp32, coalesced) ============
__global__ __launch_bounds__(256) void k_qkv(const float* __restrict__ enc,
    const float* __restrict__ wq, const float* __restrict__ wk,
    const float* __restrict__ wv, float* __restrict__ ws) {
  int l0 = blockIdx.x * TT; int b = blockIdx.y;
  int t = threadIdx.x;
  __shared__ float xs[64][12];   // [c][token]
  {
    int idx = t, c = idx >> 3, i = idx & 7;
    xs[c][i] = enc[(size_t)b * Cc * Ll + (size_t)c * Ll + l0 + i];
    idx = t + 256; c = idx >> 3; i = idx & 7;
    xs[c][i] = enc[(size_t)b * Cc * Ll + (size_t)c * Ll + l0 + i];
  }
  __syncthreads();
  ushort_t* qb = (ushort_t*)(ws + OQ);
  ushort_t* kb = (ushort_t*)(ws + OK_);
  float* v = ws + OV;
#pragma unroll
  for (int g = 0; g < 6; ++g) {
    int j = t + g * 256;
    float acc[TT];
#pragma unroll
    for (int i = 0; i < TT; ++i) acc[i] = 0.f;
    const float* wp; int col, stride;
    if (j < 512) { wp = wq + j; stride = 512; col = j; }
    else if (j < 1024) { wp = wk + (j - 512); stride = 512; col = j - 512; }
    else { wp = wv + (j - 1024); stride = 1024; col = j - 1024; }
    for (int c = 0; c < 64; ++c) {
      float w = wp[(size_t)c * stride];
      const float4* xc = (const float4*)&xs[c][0];
      float4 x0 = xc[0], x1 = xc[1];
      acc[0] += x0.x * w; acc[1] += x0.y * w;
      acc[2] += x0.z * w; acc[3] += x0.w * w;
      acc[4] += x1.x * w; acc[5] += x1.y * w;
      acc[6] += x1.z * w; acc[7] += x1.w * w;
    }
    if (j < 512) {
#pragma unroll
      for (int i = 0; i < TT; ++i)
        qb[((size_t)(b * 8 + (col >> 6)) * Ll + l0 + i) * 64 + (col & 63)] =
            (ushort_t)f2bf(acc[i] * 0.125f);
    } else if (j < 1024) {
#pragma unroll
      for (int i = 0; i < TT; ++i)
        kb[((size_t)(b * 8 + (col >> 6)) * Ll + l0 + i) * 64 + (col & 63)] =
            (ushort_t)f2bf(acc[i]);
    } else {
#pragma unroll
      for (int i = 0; i < TT; ++i)
        v[((size_t)(b * 8 + (col >> 7)) * Ll + l0 + i) * 128 + (col & 127)] = acc[i];
    }
  }
}

// ============ 1b. transpose V -> vt bf16 (bh, dv, L) ============
__global__ __launch_bounds__(256) void k_vt(float* __restrict__ ws) {
  int bh = blockIdx.y;
  int l0 = blockIdx.x * 64;
  int t = threadIdx.x;
  __shared__ float tile[128][65];
  const float* vp = ws + OV + ((size_t)bh * Ll + l0) * 128;
  for (int i = t; i < 64 * 32; i += 256) {
    int l = i >> 5, dv4 = (i & 31) * 4;
    float4 a = *(const float4*)(vp + (size_t)l * 128 + dv4);
    tile[dv4][l] = a.x; tile[dv4 + 1][l] = a.y;
    tile[dv4 + 2][l] = a.z; tile[dv4 + 3][l] = a.w;
  }
  __syncthreads();
  ushort_t* vt = (ushort_t*)(ws + OVT) + (size_t)bh * 128 * Ll + l0;
  for (int i = t; i < 128 * 16; i += 256) {
    int dv = i >> 4, l4 = (i & 15) * 4;
    short4v a;
    a[0] = f2bf(tile[dv][l4]); a[1] = f2bf(tile[dv][l4 + 1]);
    a[2] = f2bf(tile[dv][l4 + 2]); a[3] = f2bf(tile[dv][l4 + 3]);
    *(short4v*)(vt + (size_t)dv * Ll + l4) = a;
  }
}

// ============ 2. flash attention (bf16 MFMA, fixed-max softmax) ============
#define NKT 36
#define LSK 72
__global__ __launch_bounds__(256) void k_attn(const float* __restrict__ snr,
                                              float* __restrict__ ws) {
  int bh = blockIdx.y; int b = bh >> 3; int hd = bh & 7;
  int q0 = blockIdx.x * 64;
  int t = threadIdx.x;
  int w = t >> 6, lane = t & 63;
  int m16 = lane & 15, quad = lane >> 4;

  __shared__ __align__(16) ushort_t Ks[64 * LSK];
  __shared__ __align__(16) ushort_t Vs[128 * LSK];
  __shared__ __align__(16) ushort_t Ps[4 * 16 * LSK];
  __shared__ float sfac_s[64];
  __shared__ float lsc[4][16];

  const ushort_t* qbf = (const ushort_t*)(ws + OQ) + (size_t)bh * Ll * 64;
  const ushort_t* kbf = (const ushort_t*)(ws + OK_) + (size_t)bh * Ll * 64;
  const ushort_t* vtb = (const ushort_t*)(ws + OVT) + (size_t)bh * 128 * Ll;

  short8v qa[2];
  {
    const ushort_t* qrp = qbf + (size_t)(q0 + w * 16 + m16) * 64 + quad * 8;
    qa[0] = *(const short8v*)qrp;
    qa[1] = *(const short8v*)(qrp + 32);
  }
  int sk_key = t >> 2, sk_d0 = (t & 3) * 16;
  int sv_dv = t >> 1, sv_k0 = (t & 1) * 32;

  short8v kreg[2], vreg[4];
  float snr_reg = 0.f;
  {
    const ushort_t* ksrc = kbf + (size_t)sk_key * 64 + sk_d0;
    kreg[0] = *(const short8v*)ksrc;
    kreg[1] = *(const short8v*)(ksrc + 8);
    const ushort_t* vsrc = vtb + (size_t)sv_dv * Ll + sv_k0;
#pragma unroll
    for (int i = 0; i < 4; ++i) vreg[i] = *(const short8v*)(vsrc + i * 8);
    if (t < 64) snr_reg = snr[b * Ll + t];
  }

  f32x4 oacc[8];
#pragma unroll
  for (int i = 0; i < 8; ++i) oacc[i] = (f32x4)0.f;
  float l_r[4] = {0.f, 0.f, 0.f, 0.f};

  for (int kt = 0; kt < NKT; ++kt) {
    __syncthreads();
    *(short8v*)&Ks[sk_key * LSK + sk_d0] = kreg[0];
    *(short8v*)&Ks[sk_key * LSK + sk_d0 + 8] = kreg[1];
#pragma unroll
    for (int i = 0; i < 4; ++i)
      *(short8v*)&Vs[sv_dv * LSK + sv_k0 + i * 8] = vreg[i];
    if (t < 64) sfac_s[t] = snr_reg + 1e-4f;
    __syncthreads();
    if (kt + 1 < NKT) {
      int k0n = (kt + 1) * 64;
      const ushort_t* ksrc = kbf + (size_t)(k0n + sk_key) * 64 + sk_d0;
      kreg[0] = *(const short8v*)ksrc;
      kreg[1] = *(const short8v*)(ksrc + 8);
      const ushort_t* vsrc = vtb + (size_t)sv_dv * Ll + k0n + sv_k0;
#pragma unroll
      for (int i = 0; i < 4; ++i) vreg[i] = *(const short8v*)(vsrc + i * 8);
      if (t < 64) snr_reg = snr[b * Ll + k0n + t];
    }

    f32x4 sac[4];
#pragma unroll
    for (int n = 0; n < 4; ++n) {
      int key = n * 16 + m16;
      short8v kb0 = *(const short8v*)&Ks[key * LSK + quad * 8];
      short8v kb1 = *(const short8v*)&Ks[key * LSK + 32 + quad * 8];
      f32x4 acc = (f32x4)0.f;
      acc = __builtin_amdgcn_mfma_f32_16x16x32_bf16(qa[0], kb0, acc, 0, 0, 0);
      acc = __builtin_amdgcn_mfma_f32_16x16x32_bf16(qa[1], kb1, acc, 0, 0, 0);
      sac[n] = acc;
    }
    float sf[4];
#pragma unroll
    for (int n = 0; n < 4; ++n) sf[n] = sfac_s[n * 16 + m16];
    ushort_t* pw = &Ps[w * 16 * LSK];
#pragma unroll
    for (int r = 0; r < 4; ++r) {
#pragma unroll
      for (int n = 0; n < 4; ++n) {
        float p = __expf(sac[n][r]) * sf[n];
        l_r[r] += p;
        pw[(quad * 4 + r) * LSK + n * 16 + m16] = (ushort_t)f2bf(p);
      }
    }
    short8v pb0 = *(const short8v*)&pw[m16 * LSK + quad * 8];
    short8v pb1 = *(const short8v*)&pw[m16 * LSK + 32 + quad * 8];
#pragma unroll
    for (int dt_ = 0; dt_ < 8; ++dt_) {
      const ushort_t* vrow = &Vs[(dt_ * 16 + m16) * LSK];
      short8v va0 = *(const short8v*)&vrow[quad * 8];
      short8v va1 = *(const short8v*)&vrow[32 + quad * 8];
      f32x4 o = oacc[dt_];
      o = __builtin_amdgcn_mfma_f32_16x16x32_bf16(va0, pb0, o, 0, 0, 0);
      o = __builtin_amdgcn_mfma_f32_16x16x32_bf16(va1, pb1, o, 0, 0, 0);
      oacc[dt_] = o;
    }
  }
#pragma unroll
  for (int r = 0; r < 4; ++r) {
    float lv = l_r[r];
    lv += __shfl_xor(lv, 1, 64);
    lv += __shfl_xor(lv, 2, 64);
    lv += __shfl_xor(lv, 4, 64);
    lv += __shfl_xor(lv, 8, 64);
    l_r[r] = lv;
  }
  if (m16 == 0) {
#pragma unroll
    for (int r = 0; r < 4; ++r) lsc[w][quad * 4 + r] = l_r[r];
  }
  float linv = 1.f / lsc[w][m16];
  float* op = ws + OO + ((size_t)(b * Ll + q0 + w * 16 + m16)) * 1024 + hd * 128;
#pragma unroll
  for (int dt_ = 0; dt_ < 8; ++dt_) {
#pragma unroll
    for (int r = 0; r < 4; ++r) {
      op[dt_ * 16 + quad * 4 + r] = oacc[dt_][r] * linv;
    }
  }
}

// ============ 3+4. o@fc + residual + LN + xz, 8 tokens/block ============
__global__ __launch_bounds__(256) void k_oprojxz(const float* __restrict__ enc,
    const float* __restrict__ fc, const float* __restrict__ lnw,
    const float* __restrict__ lnb, const float* __restrict__ ssin,
    float* __restrict__ ws) {
  int l0 = blockIdx.x * TT, b = blockIdx.y, t = threadIdx.x;
  __shared__ float orow[1024][9];
  __shared__ float part[4][TT][64];
  __shared__ float xh_s[64][9];
  const float* op = ws + OO + ((size_t)(b * Ll + l0)) * 1024;
#pragma unroll
  for (int k = 0; k < 4; ++k) {
    int c = t + k * 256;
#pragma unroll
    for (int i = 0; i < TT; ++i) orow[c][i] = op[(size_t)i * 1024 + c];
  }
  __syncthreads();
  int col = t & 63, seg = t >> 6;
  {
    float acc[TT];
#pragma unroll
    for (int i = 0; i < TT; ++i) acc[i] = 0.f;
    const float* fcs = fc + (size_t)(seg * 256) * 64 + col;
    for (int c = 0; c < 256; ++c) {
      float w = fcs[(size_t)c * 64];
      const float* orc = &orow[seg * 256 + c][0];
#pragma unroll
      for (int i = 0; i < TT; ++i) acc[i] += orc[i] * w;
    }
#pragma unroll
    for (int i = 0; i < TT; ++i) part[seg][i][col] = acc[i];
  }
  __syncthreads();
  if (t < 64) {
    float lw = lnw[t], lb = lnb[t];
#pragma unroll
    for (int i = 0; i < TT; ++i) {
      float a = part[0][i][t] + part[1][i][t] + part[2][i][t] + part[3][i][t];
      a += enc[(size_t)b * Cc * Ll + (size_t)t * Ll + l0 + i];
      float s = a;
#pragma unroll
      for (int o = 32; o >= 1; o >>= 1) s += __shfl_xor(s, o, 64);
      float m = s * (1.f / 64.f);
      float dd = a - m;
      float vs = dd * dd;
#pragma unroll
      for (int o = 32; o >= 1; o >>= 1) vs += __shfl_xor(vs, o, 64);
      xh_s[t][i] = dd * rsqrtf(vs * (1.f / 64.f) + 1e-5f) * lw + lb;
    }
  }
  __syncthreads();
  {
    float acc2[TT];
#pragma unroll
    for (int i = 0; i < TT; ++i) acc2[i] = 0.f;
    for (int c = 0; c < 64; ++c) {
      float w = ssin[c * 256 + t];
      const float* xc = &xh_s[c][0];
#pragma unroll
      for (int i = 0; i < TT; ++i) acc2[i] += xc[i] * w;
    }
    if (t < 128) {
#pragma unroll
      for (int i = 0; i < TT; ++i)
        ws[OX1P + ((size_t)(b * Ll + l0 + i)) * 128 + t] = acc2[i];
    } else {
#pragma unroll
      for (int i = 0; i < TT; ++i)
        ws[OZ + ((size_t)(b * Ll + l0 + i)) * 128 + (t - 128)] = acc2[i];
    }
  }
}

// ============ 5. depthwise conv3x3 + bias + silu ============
__global__ __launch_bounds__(128) void k_conv(const float* __restrict__ cw,
    const float* __restrict__ cb, float* __restrict__ ws) {
  int l = blockIdx.x, b = blockIdx.y, d = threadIdx.x;
  int h = l / 48, w = l % 48;
  float acc = cb[d];
#pragma unroll
  for (int kh = 0; kh < 3; ++kh) {
    int hh = h + kh - 1;
    if (hh < 0 || hh >= 48) continue;
#pragma unroll
    for (int kw = 0; kw < 3; ++kw) {
      int wx = w + kw - 1;
      if (wx < 0 || wx >= 48) continue;
      acc += ws[OX1P + ((size_t)b * Ll + hh * 48 + wx) * 128 + d] *
             cw[d * 9 + kh * 3 + kw];
    }
  }
  ws[OX1S + ((size_t)b * Ll + l) * 128 + d] = siluf(acc);
}

// ============ 6. x_dbl projections, 8 tokens/block ============
__global__ __launch_bounds__(128) void k_xdbl(const float* __restrict__ xw,
    const float* __restrict__ dtw, const float* __restrict__ dtb,
    float* __restrict__ ws) {
  int l0 = blockIdx.x * TT;
  int by = blockIdx.y; int b = by >> 2; int k = by & 3;
  int t = threadIdx.x;
  __shared__ float xv[128][9];
  __shared__ float pr[36][TT];
#pragma unroll
  for (int i = 0; i < TT; ++i) {
    int sp = spmap(k, l0 + i);
    xv[t][i] = ws[OX1S + ((size_t)(b * Ll) + sp) * 128 + t];
  }
  __syncthreads();
  if (t < 36) {
    float s[TT];
#pragma unroll
    for (int i = 0; i < TT; ++i) s[i] = 0.f;
    const float* wp = xw + (size_t)(k * 36 + t) * 128;
    for (int d = 0; d < 128; ++d) {
      float w = wp[d];
      const float* xc = &xv[d][0];
#pragma unroll
      for (int i = 0; i < TT; ++i) s[i] += xc[i] * w;
    }
#pragma unroll
    for (int i = 0; i < TT; ++i) pr[t][i] = s[i];
  }
  __syncthreads();
  {
    int d = t;
    const float* wp = dtw + (size_t)(k * 128 + d) * 4;
    float w0 = wp[0], w1 = wp[1], w2 = wp[2], w3 = wp[3];
    float bb = dtb[k * 128 + d];
#pragma unroll
    for (int i = 0; i < TT; ++i) {
      float v = pr[0][i] * w0 + pr[1][i] * w1 + pr[2][i] * w2 + pr[3][i] * w3 + bb;
      ws[ODT2 + ((size_t)(by * Ll + l0 + i)) * 128 + d] = softplusf(v);
    }
  }
  if (t < 16) {
#pragma unroll
    for (int i = 0; i < TT; ++i)
      ws[OBS2 + ((size_t)(by * Ll + l0 + i)) * 16 + t] = pr[4 + t][i];
  } else if (t < 32) {
#pragma unroll
    for (int i = 0; i < TT; ++i)
      ws[OCS2 + ((size_t)(by * Ll + l0 + i)) * 16 + (t - 16)] = pr[20 + (t - 16)][i];
  }
}

// ============ 7a. scan phase A ============
__global__ __launch_bounds__(256) void k_scanA(const float* __restrict__ alog,
                                               float* __restrict__ ws) {
  int c = blockIdx.x;
  int bk = blockIdx.y;
  int b = bk >> 2, k = bk & 3;
  int t = threadIdx.x;
  int n = t & 15, dg = t >> 4;
  __shared__ float dt_s[128], x_s[128], Bs_s[16];
  float A_r[8], ap[8], bc[8];
#pragma unroll
  for (int i = 0; i < 8; ++i) {
    int d = dg * 8 + i;
    A_r[i] = -__expf(alog[(size_t)((k * 128 + d) * 16) + n]);
    ap[i] = 1.f; bc[i] = 0.f;
  }
  const float* dtp = ws + ODT2 + ((size_t)bk * Ll) * 128;
  const float* bsp = ws + OBS2 + ((size_t)bk * Ll) * 16;
  const float* xb = ws + OX1S + (size_t)b * Ll * 128;
  for (int ll = 0; ll < SCH; ++ll) {
    int l = c * SCH + ll;
    int sp = spmap(k, l);
    if (t < 128) dt_s[t] = dtp[(size_t)l * 128 + t];
    else x_s[t - 128] = xb[(size_t)sp * 128 + (t - 128)];
    if (t < 16) Bs_s[t] = bsp[(size_t)l * 16 + t];
    __syncthreads();
    float Bv = Bs_s[n];
#pragma unroll
    for (int i = 0; i < 8; ++i) {
      int d = dg * 8 + i;
      float dtv = dt_s[d];
      float a = __expf(dtv * A_r[i]);
      bc[i] = bc[i] * a + dtv * x_s[d] * Bv;
      ap[i] *= a;
    }
    __syncthreads();
  }
  float* csa = ws + OCSA + ((size_t)(bk * SNC + c) * 128) * 16;
  float* csb = ws + OCSB + ((size_t)(bk * SNC + c) * 128) * 16;
#pragma unroll
  for (int i = 0; i < 8; ++i) {
    int d = dg * 8 + i;
    csa[d * 16 + n] = ap[i];
    csb[d * 16 + n] = bc[i];
  }
}

// ============ 7b. scan phase B ============
__global__ __launch_bounds__(256) void k_scanB(float* __restrict__ ws) {
  int g = blockIdx.x * 256 + threadIdx.x;
  int bk = g >> 11;
  int dn = g & 2047;
  const float* csa = ws + OCSA;
  const float* csb = ws + OCSB;
  float* hst = ws + OHST;
  float h = 0.f;
  for (int c = 0; c < SNC; ++c) {
    size_t idx = (size_t)(bk * SNC + c) * 2048 + dn;
    hst[idx] = h;
    h = csa[idx] * h + csb[idx];
  }
}

// ============ 7c. scan phase C ============
__global__ __launch_bounds__(256) void k_scanC(const float* __restrict__ alog,
    const float* __restrict__ Dp, float* __restrict__ ws) {
  int c = blockIdx.x, bk = blockIdx.y;
  int b = bk >> 2, k = bk & 3;
  int t = threadIdx.x;
  int n = t & 15, dg = t >> 4;
  __shared__ float dt_s[128], x_s[128], Bs_s[16], Cs_s[16];
  float A_r[8], h[8], Dv[8];
#pragma unroll
  for (int i = 0; i < 8; ++i) {
    int d = dg * 8 + i;
    A_r[i] = -__expf(alog[(size_t)((k * 128 + d) * 16) + n]);
    h[i] = ws[OHST + ((size_t)(bk * SNC + c) * 128 + d) * 16 + n];
    Dv[i] = Dp[k * 128 + d];
  }
  const float* dtp = ws + ODT2 + ((size_t)bk * Ll) * 128;
  const float* bsp = ws + OBS2 + ((size_t)bk * Ll) * 16;
  const float* csp = ws + OCS2 + ((size_t)bk * Ll) * 16;
  const float* xb = ws + OX1S + (size_t)b * Ll * 128;
  float* yp = ws + OYS2 + ((size_t)bk * Ll) * 128;
  for (int ll = 0; ll < SCH; ++ll) {
    int l = c * SCH + ll;
    int sp = spmap(k, l);
    if (t < 128) dt_s[t] = dtp[(size_t)l * 128 + t];
    else x_s[t - 128] = xb[(size_t)sp * 128 + (t - 128)];
    if (t < 16) Bs_s[t] = bsp[(size_t)l * 16 + t];
    else if (t < 32) Cs_s[t - 16] = csp[(size_t)l * 16 + (t - 16)];
    __syncthreads();
    float Bv = Bs_s[n], Cv = Cs_s[n];
    float yacc[8];
#pragma unroll
    for (int i = 0; i < 8; ++i) {
      int d = dg * 8 + i;
      float dtv = dt_s[d];
      float a = __expf(dtv * A_r[i]);
      h[i] = h[i] * a + dtv * x_s[d] * Bv;
      yacc[i] = h[i] * Cv;
    }
#pragma unroll
    for (int i = 0; i < 8; ++i) {
      float yv = yacc[i];
      yv += __shfl_xor(yv, 1, 64);
      yv += __shfl_xor(yv, 2, 64);
      yv += __shfl_xor(yv, 4, 64);
      yv += __shfl_xor(yv, 8, 64);
      yacc[i] = yv;
    }
    if (n == 0) {
#pragma unroll
      for (int i = 0; i < 8; ++i) {
        int d = dg * 8 + i;
        yp[(size_t)l * 128 + d] = yacc[i] + Dv[i] * x_s[d];
      }
    }
    __syncthreads();
  }
}

// ============ 8. combine dirs + LN + gate ============
__global__ __launch_bounds__(128) void k_comb(const float* __restrict__ nw,
    const float* __restrict__ nb, const float* __restrict__ snr,
    float* __restrict__ ws) {
  int l = blockIdx.x, b = blockIdx.y, d = threadIdx.x;
  int h = l / 48, w = l % 48;
  int lT = w * 48 + h;
  const float* ysb = ws + OYS2;
  float v = ysb[((size_t)(b * 4 + 0) * Ll + l) * 128 + d] +
            ysb[((size_t)(b * 4 + 2) * Ll + (2303 - l)) * 128 + d] +
            ysb[((size_t)(b * 4 + 1) * Ll + lT) * 128 + d] +
            ysb[((size_t)(b * 4 + 3) * Ll + (2303 - lT)) * 128 + d];
  __shared__ float red[4];
  int lane = d & 63, wid = d >> 6;
  float s = v;
#pragma unroll
  for (int o = 32; o >= 1; o >>= 1) s += __shfl_xor(s, o, 64);
  if (lane == 0) red[wid] = s;
  __syncthreads();
  float m = (red[0] + red[1]) * (1.f / 128.f);
  float dv_ = v - m;
  float q = dv_ * dv_;
#pragma unroll
  for (int o = 32; o >= 1; o >>= 1) q += __shfl_xor(q, o, 64);
  if (lane == 0) red[wid + 2] = q;
  __syncthreads();
  float var = (red[2] + red[3]) * (1.f / 128.f);
  float y = dv_ * rsqrtf(var + 1e-5f) * nw[d] + nb[d];
  float zv = ws[OZ + ((size_t)b * Ll + l) * 128 + d];
  y *= siluf(zv);
  y *= snr[b * Ll + l];
  ws[OY2 + ((size_t)b * Ll + l) * 128 + d] = y;
}

// ============ 9+10. x2 + LN + FFN conv1 + gelu, 8 tokens/block ============
__global__ __launch_bounds__(256) void k_outffn1(const float* __restrict__ enc,
    const float* __restrict__ ow, const float* __restrict__ lw,
    const float* __restrict__ lb, const float* __restrict__ w1,
    float* __restrict__ ws) {
  int l0 = blockIdx.x * TT, b = blockIdx.y, t = threadIdx.x;
  __shared__ float yr[128][9];
  __shared__ float part[2][TT][64];
  __shared__ float xn_s[64][9];
  const float* yp = ws + OY2 + ((size_t)(b * Ll + l0)) * 128;
  if (t < 128) {
#pragma unroll
    for (int i = 0; i < TT; ++i) yr[t][i] = yp[(size_t)i * 128 + t];
  }
  __syncthreads();
  if (t < 128) {
    int col = t & 63, seg = t >> 6;
    float acc[TT];
#pragma unroll
    for (int i = 0; i < TT; ++i) acc[i] = 0.f;
    const float* ows = ow + (size_t)(seg * 64) * 64 + col;
    for (int c = 0; c < 64; ++c) {
      float w = ows[c * 64];
      const float* yc = &yr[seg * 64 + c][0];
#pragma unroll
      for (int i = 0; i < TT; ++i) acc[i] += yc[i] * w;
    }
#pragma unroll
    for (int i = 0; i < TT; ++i) part[seg][i][col] = acc[i];
  }
  __syncthreads();
  if (t < 64) {
    float lwv = lw[t], lbv = lb[t];
#pragma unroll
    for (int i = 0; i < TT; ++i) {
      float a = part[0][i][t] + part[1][i][t];
      a += enc[(size_t)b * Cc * Ll + (size_t)t * Ll + l0 + i];
      ws[OX2 + ((size_t)(b * Ll + l0 + i)) * 64 + t] = a;
      float s = a;
#pragma unroll
      for (int o = 32; o >= 1; o >>= 1) s += __shfl_xor(s, o, 64);
      float m = s * (1.f / 64.f);
      float dd2 = a - m;
      float vs = dd2 * dd2;
#pragma unroll
      for (int o = 32; o >= 1; o >>= 1) vs += __shfl_xor(vs, o, 64);
      xn_s[t][i] = dd2 * rsqrtf(vs * (1.f / 64.f) + 1e-5f) * lwv + lbv;
    }
  }
  __syncthreads();
  {
    float acc2[TT];
#pragma unroll
    for (int i = 0; i < TT; ++i) acc2[i] = 0.f;
    const float* wp = w1 + (size_t)t * 64;
    for (int c = 0; c < 64; ++c) {
      float w = wp[c];
      const float* xc = &xn_s[c][0];
#pragma unroll
      for (int i = 0; i < TT; ++i) acc2[i] += xc[i] * w;
    }
#pragma unroll
    for (int i = 0; i < TT; ++i)
      ws[OH1A + ((size_t)(b * Ll + l0 + i)) * 256 + t] = geluf(acc2[i]);
  }
}

// ============ 11. FFN depthwise 3x3 + gelu ============
__global__ __launch_bounds__(256) void k_ffndw(const float* __restrict__ dww,
                                               float* __restrict__ ws) {
  int l = blockIdx.x, b = blockIdx.y, mch = threadIdx.x;
  int h = l / 48, w = l % 48;
  float acc = 0.f;
#pragma unroll
  for (int kh = 0; kh < 3; ++kh) {
    int hh = h + kh - 1;
    if (hh < 0 || hh >= 48) continue;
#pragma unroll
    for (int kw = 0; kw < 3; ++kw) {
      int wx = w + kw - 1;
      if (wx < 0 || wx >= 48) continue;
      acc += ws[OH1A + ((size_t)b * Ll + hh * 48 + wx) * 256 + mch] *
             dww[mch * 9 + kh * 3 + kw];
    }
  }
  ws[OH1B + ((size_t)b * Ll + l) * 256 + mch] = geluf(acc);
}

// ============ 12. FFN conv2 1x1 + residual + transposed out, 8 tokens/block ============
__global__ __launch_bounds__(256) void k_ffn2(const float* __restrict__ w2,
                                              float* __restrict__ ws,
                                              float* __restrict__ out) {
  int l0 = blockIdx.x * TT, b = blockIdx.y, t = threadIdx.x;
  __shared__ float hr[256][9];
  __shared__ float part[4][TT][64];
  const float* hp = ws + OH1B + ((size_t)(b * Ll + l0)) * 256;
#pragma unroll
  for (int i = 0; i < TT; ++i) hr[t][i] = hp[(size_t)i * 256 + t];
  __syncthreads();
  int col = t & 63, seg = t >> 6;
  {
    float acc[TT];
#pragma unroll
    for (int i = 0; i < TT; ++i) acc[i] = 0.f;
    const float* wp = w2 + (size_t)col * 256 + seg * 64;
    for (int c = 0; c < 64; ++c) {
      float w = wp[c];
      const float* hc = &hr[seg * 64 + c][0];
#pragma unroll
      for (int i = 0; i < TT; ++i) acc[i] += hc[i] * w;
    }
#pragma unroll
    for (int i = 0; i < TT; ++i) part[seg][i][col] = acc[i];
  }
  __syncthreads();
  if (t < 64) {
    float av[TT];
#pragma unroll
    for (int i = 0; i < TT; ++i) {
      float a = part[0][i][t] + part[1][i][t] + part[2][i][t] + part[3][i][t];
      av[i] = a + ws[OX2 + ((size_t)(b * Ll + l0 + i)) * 64 + t];
    }
    float* opx = out + ((size_t)(b * 64 + t)) * 2304 + l0;
    *(float4*)opx = make_float4(av[0], av[1], av[2], av[3]);
    *((float4*)opx + 1) = make_float4(av[4], av[5], av[6], av[7]);
  }
}

extern "C" void kernel_launch(void* const* d_in, const int* in_sizes, int n_in,
                              void* d_out, int out_size, void* d_ws, size_t ws_size,
                              hipStream_t stream) {
  (void)in_sizes; (void)n_in; (void)out_size;
  const float* enc  = (const float*)d_in[0];
  const float* snr  = (const float*)d_in[1];
  const float* wq   = (const float*)d_in[2];
  const float* wk   = (const float*)d_in[3];
  const float* wv   = (const float*)d_in[4];
  const float* fc   = (const float*)d_in[5];
  const float* alnw = (const float*)d_in[6];
  const float* alnb = (const float*)d_in[7];
  const float* ssin = (const float*)d_in[8];
  const float* cw   = (const float*)d_in[9];
  const float* cb   = (const float*)d_in[10];
  const float* xw   = (const float*)d_in[11];
  const float* dtw  = (const float*)d_in[12];
  const float* dtb  = (const float*)d_in[13];
  const float* alog = (const float*)d_in[14];
  const float* Dp   = (const float*)d_in[15];
  const float* nw   = (const float*)d_in[16];
  const float* nb   = (const float*)d_in[17];
  const float* ow   = (const float*)d_in[18];
  const float* flnw = (const float*)d_in[19];
  const float* flnb = (const float*)d_in[20];
  const float* w1   = (const float*)d_in[21];
  const float* dww  = (const float*)d_in[22];
  const float* w2   = (const float*)d_in[23];
  float* ws = (float*)d_ws;
  float* out = (float*)d_out;

  if (ws_size < (size_t)WS_NEED_FLOATS * 4) {
    hipLaunchKernelGGL(k_code, dim3(1), dim3(64), 0, stream, out);
    return;
  }

  hipLaunchKernelGGL(k_qkv, dim3(Ll / TT, Bq), dim3(256), 0, stream, enc, wq, wk, wv, ws);
  hipLaunchKernelGGL(k_vt, dim3(Ll / 64, Bq * NHh), dim3(256), 0, stream, ws);
  hipLaunchKernelGGL(k_attn, dim3(Ll / 64, Bq * NHh), dim3(256), 0, stream, snr, ws);
  hipLaunchKernelGGL(k_oprojxz, dim3(Ll / TT, Bq), dim3(256), 0, stream, enc, fc, alnw, alnb, ssin, ws);
  hipLaunchKernelGGL(k_conv, dim3(Ll, Bq), dim3(128), 0, stream, cw, cb, ws);
  hipLaunchKernelGGL(k_xdbl, dim3(Ll / TT, Bq * 4), dim3(128), 0, stream, xw, dtw, dtb, ws);
  hipLaunchKernelGGL(k_scanA, dim3(SNC, Bq * 4), dim3(256), 0, stream, alog, ws);
  hipLaunchKernelGGL(k_scanB, dim3(64), dim3(256), 0, stream, ws);
  hipLaunchKernelGGL(k_scanC, dim3(SNC, Bq * 4), dim3(256), 0, stream, alog, Dp, ws);
  hipLaunchKernelGGL(k_comb, dim3(Ll, Bq), dim3(128), 0, stream, nw, nb, snr, ws);
  hipLaunchKernelGGL(k_outffn1, dim3(Ll / TT, Bq), dim3(256), 0, stream, enc, ow, flnw, flnb, w1, ws);
  hipLaunchKernelGGL(k_ffndw, dim3(Ll, Bq), dim3(256), 0, stream, dww, ws);
  hipLaunchKernelGGL(k_ffn2, dim3(Ll / TT, Bq), dim3(256), 0, stream, w2, ws, out);
}

// Round 13
// 434.162 us; speedup vs baseline: 1.3472x; 1.0623x over previous
//
#include <hip/hip_runtime.h>
#include <hip/hip_bf16.h>

#define Bq 2
#define Cc 64
#define Hh 48
#define Ww 48
#define Ll 2304
#define NHh 8
#define DKk 64
#define DVv 128
#define DNn 128
#define NSs 16
#define Rr 4
#define SCH 48
#define SNC 48
#define TT 8      // tokens per block in GEMM-ish kernels

// ---- workspace layout (float offsets) ----
#define OQ    0u                 // (B*8, L, 64) Q bf16 (ushort), pre-scaled by 1/8
#define OK_   2359296u           // (B*8, L, 64) K bf16 (ushort)
#define OV    4718592u           // (B*8, L, 128) V fp32
#define OO    9437184u           // (B, L, 1024) attention out fp32
#define OY2   14450688u          // (unused now)
#define OX2   15040512u
#define OXN   15335424u
#define OVT   15630336u          // (B*8, 128, L) V^T bf16 (ushort)
#define WS_NEED_FLOATS (OVT + 4718592u)
// aliases (lifetimes: q,k,v,vt dead after k_attn; o dead after k_oprojxz)
#define ODT2  OQ                 // (B*4, L, 128) dt, l-major
#define OYS2  OK_                // (B*4, L, 128) scan y, l-major
#define OX1P  OV                 // (B,L,128)
#define OZ    (OV + 589824u)     // (B,L,128)
#define OX1S  (OV + 1179648u)    // (B,L,128)
#define OBS2  (OV + 1769472u)    // (B*4, L, 16)
#define OCS2  (OV + 2064384u)    // (B*4, L, 16)
#define OCSA  (OV + 2359296u)    // (B*4, SNC, 128, 16)
#define OCSB  (OV + 3145728u)    // (B*4, SNC, 128, 16)
#define OHST  (OV + 3932160u)    // (B*4, SNC, 128, 16)
#define OH1A  OO                 // (B,L,256)
#define OH1B  (OO + 1179648u)    // (B,L,256)

typedef short short8v __attribute__((ext_vector_type(8)));
typedef short short4v __attribute__((ext_vector_type(4)));
typedef float f32x4 __attribute__((ext_vector_type(4)));
typedef unsigned short ushort_t;

__device__ __forceinline__ float geluf(float x) {
  return 0.5f * x * (1.0f + erff(x * 0.70710678118654752f));
}
__device__ __forceinline__ float siluf(float x) {
  return x / (1.0f + __expf(-x));
}
__device__ __forceinline__ float softplusf(float x) {
  return fmaxf(x, 0.0f) + log1pf(__expf(-fabsf(x)));
}
__device__ __forceinline__ int spmap(int k, int l) {
  if (k == 0) return l;
  if (k == 1) return (l % 48) * 48 + l / 48;
  if (k == 2) return 2303 - l;
  int l2 = 2303 - l; return (l2 % 48) * 48 + l2 / 48;
}
__device__ __forceinline__ short f2bf(float f) {
  unsigned u = __float_as_uint(f);
  unsigned r = (u + 0x7FFFu + ((u >> 16) & 1u)) >> 16;
  return (short)r;
}

__global__ void k_code(float* out) { if (threadIdx.x == 0) out[0] = 25000.f; }

// ============ 1. QKV projection, 8 tokens/block (V fp32, coalesced) ============
__global__ __launch_bounds__(256) void k_qkv(const float* __restrict__ enc,
    const float* __restrict__ wq, const float* __restrict__ wk,
    const float* __restrict__ wv, float* __restrict__ ws) {
  int l0 = blockIdx.x * TT; int b = blockIdx.y;
  int t = threadIdx.x;
  __shared__ float xs[64][12];   // [c][token]
  {
    int idx = t, c = idx >> 3, i = idx & 7;
    xs[c][i] = enc[(size_t)b * Cc * Ll + (size_t)c * Ll + l0 + i];
    idx = t + 256; c = idx >> 3; i = idx & 7;
    xs[c][i] = enc[(size_t)b * Cc * Ll + (size_t)c * Ll + l0 + i];
  }
  __syncthreads();
  ushort_t* qb = (ushort_t*)(ws + OQ);
  ushort_t* kb = (ushort_t*)(ws + OK_);
  float* v = ws + OV;
#pragma unroll
  for (int g = 0; g < 6; ++g) {
    int j = t + g * 256;
    float acc[TT];
#pragma unroll
    for (int i = 0; i < TT; ++i) acc[i] = 0.f;
    const float* wp; int col, stride;
    if (j < 512) { wp = wq + j; stride = 512; col = j; }
    else if (j < 1024) { wp = wk + (j - 512); stride = 512; col = j - 512; }
    else { wp = wv + (j - 1024); stride = 1024; col = j - 1024; }
    for (int c = 0; c < 64; ++c) {
      float w = wp[(size_t)c * stride];
      const float4* xc = (const float4*)&xs[c][0];
      float4 x0 = xc[0], x1 = xc[1];
      acc[0] += x0.x * w; acc[1] += x0.y * w;
      acc[2] += x0.z * w; acc[3] += x0.w * w;
      acc[4] += x1.x * w; acc[5] += x1.y * w;
      acc[6] += x1.z * w; acc[7] += x1.w * w;
    }
    if (j < 512) {
#pragma unroll
      for (int i = 0; i < TT; ++i)
        qb[((size_t)(b * 8 + (col >> 6)) * Ll + l0 + i) * 64 + (col & 63)] =
            (ushort_t)f2bf(acc[i] * 0.125f);
    } else if (j < 1024) {
#pragma unroll
      for (int i = 0; i < TT; ++i)
        kb[((size_t)(b * 8 + (col >> 6)) * Ll + l0 + i) * 64 + (col & 63)] =
            (ushort_t)f2bf(acc[i]);
    } else {
#pragma unroll
      for (int i = 0; i < TT; ++i)
        v[((size_t)(b * 8 + (col >> 7)) * Ll + l0 + i) * 128 + (col & 127)] = acc[i];
    }
  }
}

// ============ 1b. transpose V -> vt bf16 (bh, dv, L) ============
__global__ __launch_bounds__(256) void k_vt(float* __restrict__ ws) {
  int bh = blockIdx.y;
  int l0 = blockIdx.x * 64;
  int t = threadIdx.x;
  __shared__ float tile[128][65];
  const float* vp = ws + OV + ((size_t)bh * Ll + l0) * 128;
  for (int i = t; i < 64 * 32; i += 256) {
    int l = i >> 5, dv4 = (i & 31) * 4;
    float4 a = *(const float4*)(vp + (size_t)l * 128 + dv4);
    tile[dv4][l] = a.x; tile[dv4 + 1][l] = a.y;
    tile[dv4 + 2][l] = a.z; tile[dv4 + 3][l] = a.w;
  }
  __syncthreads();
  ushort_t* vt = (ushort_t*)(ws + OVT) + (size_t)bh * 128 * Ll + l0;
  for (int i = t; i < 128 * 16; i += 256) {
    int dv = i >> 4, l4 = (i & 15) * 4;
    short4v a;
    a[0] = f2bf(tile[dv][l4]); a[1] = f2bf(tile[dv][l4 + 1]);
    a[2] = f2bf(tile[dv][l4 + 2]); a[3] = f2bf(tile[dv][l4 + 3]);
    *(short4v*)(vt + (size_t)dv * Ll + l4) = a;
  }
}

// ============ 2. flash attention (bf16 MFMA, fixed-max softmax) ============
#define NKT 36
#define LSK 72
__global__ __launch_bounds__(256) void k_attn(const float* __restrict__ snr,
                                              float* __restrict__ ws) {
  int bh = blockIdx.y; int b = bh >> 3; int hd = bh & 7;
  int q0 = blockIdx.x * 64;
  int t = threadIdx.x;
  int w = t >> 6, lane = t & 63;
  int m16 = lane & 15, quad = lane >> 4;

  __shared__ __align__(16) ushort_t Ks[64 * LSK];
  __shared__ __align__(16) ushort_t Vs[128 * LSK];
  __shared__ __align__(16) ushort_t Ps[4 * 16 * LSK];
  __shared__ float sfac_s[64];
  __shared__ float lsc[4][16];

  const ushort_t* qbf = (const ushort_t*)(ws + OQ) + (size_t)bh * Ll * 64;
  const ushort_t* kbf = (const ushort_t*)(ws + OK_) + (size_t)bh * Ll * 64;
  const ushort_t* vtb = (const ushort_t*)(ws + OVT) + (size_t)bh * 128 * Ll;

  short8v qa[2];
  {
    const ushort_t* qrp = qbf + (size_t)(q0 + w * 16 + m16) * 64 + quad * 8;
    qa[0] = *(const short8v*)qrp;
    qa[1] = *(const short8v*)(qrp + 32);
  }
  int sk_key = t >> 2, sk_d0 = (t & 3) * 16;
  int sv_dv = t >> 1, sv_k0 = (t & 1) * 32;

  short8v kreg[2], vreg[4];
  float snr_reg = 0.f;
  {
    const ushort_t* ksrc = kbf + (size_t)sk_key * 64 + sk_d0;
    kreg[0] = *(const short8v*)ksrc;
    kreg[1] = *(const short8v*)(ksrc + 8);
    const ushort_t* vsrc = vtb + (size_t)sv_dv * Ll + sv_k0;
#pragma unroll
    for (int i = 0; i < 4; ++i) vreg[i] = *(const short8v*)(vsrc + i * 8);
    if (t < 64) snr_reg = snr[b * Ll + t];
  }

  f32x4 oacc[8];
#pragma unroll
  for (int i = 0; i < 8; ++i) oacc[i] = (f32x4)0.f;
  float l_r[4] = {0.f, 0.f, 0.f, 0.f};

  for (int kt = 0; kt < NKT; ++kt) {
    __syncthreads();
    *(short8v*)&Ks[sk_key * LSK + sk_d0] = kreg[0];
    *(short8v*)&Ks[sk_key * LSK + sk_d0 + 8] = kreg[1];
#pragma unroll
    for (int i = 0; i < 4; ++i)
      *(short8v*)&Vs[sv_dv * LSK + sv_k0 + i * 8] = vreg[i];
    if (t < 64) sfac_s[t] = snr_reg + 1e-4f;
    __syncthreads();
    if (kt + 1 < NKT) {
      int k0n = (kt + 1) * 64;
      const ushort_t* ksrc = kbf + (size_t)(k0n + sk_key) * 64 + sk_d0;
      kreg[0] = *(const short8v*)ksrc;
      kreg[1] = *(const short8v*)(ksrc + 8);
      const ushort_t* vsrc = vtb + (size_t)sv_dv * Ll + k0n + sv_k0;
#pragma unroll
      for (int i = 0; i < 4; ++i) vreg[i] = *(const short8v*)(vsrc + i * 8);
      if (t < 64) snr_reg = snr[b * Ll + k0n + t];
    }

    f32x4 sac[4];
#pragma unroll
    for (int n = 0; n < 4; ++n) {
      int key = n * 16 + m16;
      short8v kb0 = *(const short8v*)&Ks[key * LSK + quad * 8];
      short8v kb1 = *(const short8v*)&Ks[key * LSK + 32 + quad * 8];
      f32x4 acc = (f32x4)0.f;
      acc = __builtin_amdgcn_mfma_f32_16x16x32_bf16(qa[0], kb0, acc, 0, 0, 0);
      acc = __builtin_amdgcn_mfma_f32_16x16x32_bf16(qa[1], kb1, acc, 0, 0, 0);
      sac[n] = acc;
    }
    float sf[4];
#pragma unroll
    for (int n = 0; n < 4; ++n) sf[n] = sfac_s[n * 16 + m16];
    ushort_t* pw = &Ps[w * 16 * LSK];
#pragma unroll
    for (int r = 0; r < 4; ++r) {
#pragma unroll
      for (int n = 0; n < 4; ++n) {
        float p = __expf(sac[n][r]) * sf[n];
        l_r[r] += p;
        pw[(quad * 4 + r) * LSK + n * 16 + m16] = (ushort_t)f2bf(p);
      }
    }
    short8v pb0 = *(const short8v*)&pw[m16 * LSK + quad * 8];
    short8v pb1 = *(const short8v*)&pw[m16 * LSK + 32 + quad * 8];
#pragma unroll
    for (int dt_ = 0; dt_ < 8; ++dt_) {
      const ushort_t* vrow = &Vs[(dt_ * 16 + m16) * LSK];
      short8v va0 = *(const short8v*)&vrow[quad * 8];
      short8v va1 = *(const short8v*)&vrow[32 + quad * 8];
      f32x4 o = oacc[dt_];
      o = __builtin_amdgcn_mfma_f32_16x16x32_bf16(va0, pb0, o, 0, 0, 0);
      o = __builtin_amdgcn_mfma_f32_16x16x32_bf16(va1, pb1, o, 0, 0, 0);
      oacc[dt_] = o;
    }
  }
#pragma unroll
  for (int r = 0; r < 4; ++r) {
    float lv = l_r[r];
    lv += __shfl_xor(lv, 1, 64);
    lv += __shfl_xor(lv, 2, 64);
    lv += __shfl_xor(lv, 4, 64);
    lv += __shfl_xor(lv, 8, 64);
    l_r[r] = lv;
  }
  if (m16 == 0) {
#pragma unroll
    for (int r = 0; r < 4; ++r) lsc[w][quad * 4 + r] = l_r[r];
  }
  float linv = 1.f / lsc[w][m16];
  float* op = ws + OO + ((size_t)(b * Ll + q0 + w * 16 + m16)) * 1024 + hd * 128;
#pragma unroll
  for (int dt_ = 0; dt_ < 8; ++dt_) {
#pragma unroll
    for (int r = 0; r < 4; ++r) {
      op[dt_ * 16 + quad * 4 + r] = oacc[dt_][r] * linv;
    }
  }
}

// ============ 3+4. o@fc + residual + LN + xz, 8 tokens/block ============
__global__ __launch_bounds__(256) void k_oprojxz(const float* __restrict__ enc,
    const float* __restrict__ fc, const float* __restrict__ lnw,
    const float* __restrict__ lnb, const float* __restrict__ ssin,
    float* __restrict__ ws) {
  int l0 = blockIdx.x * TT, b = blockIdx.y, t = threadIdx.x;
  __shared__ float orow[1024][9];
  __shared__ float part[4][TT][64];
  __shared__ float xh_s[64][9];
  const float* op = ws + OO + ((size_t)(b * Ll + l0)) * 1024;
#pragma unroll
  for (int k = 0; k < 4; ++k) {
    int c = t + k * 256;
#pragma unroll
    for (int i = 0; i < TT; ++i) orow[c][i] = op[(size_t)i * 1024 + c];
  }
  __syncthreads();
  int col = t & 63, seg = t >> 6;
  {
    float acc[TT];
#pragma unroll
    for (int i = 0; i < TT; ++i) acc[i] = 0.f;
    const float* fcs = fc + (size_t)(seg * 256) * 64 + col;
    for (int c = 0; c < 256; ++c) {
      float w = fcs[(size_t)c * 64];
      const float* orc = &orow[seg * 256 + c][0];
#pragma unroll
      for (int i = 0; i < TT; ++i) acc[i] += orc[i] * w;
    }
#pragma unroll
    for (int i = 0; i < TT; ++i) part[seg][i][col] = acc[i];
  }
  __syncthreads();
  if (t < 64) {
    float lw = lnw[t], lb = lnb[t];
#pragma unroll
    for (int i = 0; i < TT; ++i) {
      float a = part[0][i][t] + part[1][i][t] + part[2][i][t] + part[3][i][t];
      a += enc[(size_t)b * Cc * Ll + (size_t)t * Ll + l0 + i];
      float s = a;
#pragma unroll
      for (int o = 32; o >= 1; o >>= 1) s += __shfl_xor(s, o, 64);
      float m = s * (1.f / 64.f);
      float dd = a - m;
      float vs = dd * dd;
#pragma unroll
      for (int o = 32; o >= 1; o >>= 1) vs += __shfl_xor(vs, o, 64);
      xh_s[t][i] = dd * rsqrtf(vs * (1.f / 64.f) + 1e-5f) * lw + lb;
    }
  }
  __syncthreads();
  {
    float acc2[TT];
#pragma unroll
    for (int i = 0; i < TT; ++i) acc2[i] = 0.f;
    for (int c = 0; c < 64; ++c) {
      float w = ssin[c * 256 + t];
      const float* xc = &xh_s[c][0];
#pragma unroll
      for (int i = 0; i < TT; ++i) acc2[i] += xc[i] * w;
    }
    if (t < 128) {
#pragma unroll
      for (int i = 0; i < TT; ++i)
        ws[OX1P + ((size_t)(b * Ll + l0 + i)) * 128 + t] = acc2[i];
    } else {
#pragma unroll
      for (int i = 0; i < TT; ++i)
        ws[OZ + ((size_t)(b * Ll + l0 + i)) * 128 + (t - 128)] = acc2[i];
    }
  }
}

// ============ 5. depthwise conv3x3 + bias + silu, 8 tokens/block ============
__global__ __launch_bounds__(256) void k_conv(const float* __restrict__ cw,
    const float* __restrict__ cb, float* __restrict__ ws) {
  int l0 = blockIdx.x * TT, b = blockIdx.y, t = threadIdx.x;
  int h = l0 / 48, w0 = l0 % 48;   // 8 tokens share row h (48 % 8 == 0)
  __shared__ float tile[3][10][128];
  for (int idx = t; idx < 3840; idx += 256) {
    int r = idx / 1280, rem = idx % 1280;
    int col = rem >> 7, d = rem & 127;
    int hh = h + r - 1, wx = w0 + col - 1;
    float v = 0.f;
    if (hh >= 0 && hh < 48 && wx >= 0 && wx < 48)
      v = ws[OX1P + ((size_t)(b * Ll + hh * 48 + wx)) * 128 + d];
    tile[r][col][d] = v;
  }
  __syncthreads();
  int d = t & 127, half = t >> 7;
  float cwr[9];
#pragma unroll
  for (int j = 0; j < 9; ++j) cwr[j] = cw[d * 9 + j];
  float cbv = cb[d];
#pragma unroll
  for (int j = 0; j < 4; ++j) {
    int i = half * 4 + j;
    float acc = cbv;
#pragma unroll
    for (int kh = 0; kh < 3; ++kh)
#pragma unroll
      for (int kw = 0; kw < 3; ++kw)
        acc += tile[kh][i + kw][d] * cwr[kh * 3 + kw];
    ws[OX1S + ((size_t)(b * Ll + l0 + i)) * 128 + d] = siluf(acc);
  }
}

// ============ 6. x_dbl projections, 8 tokens/block ============
__global__ __launch_bounds__(128) void k_xdbl(const float* __restrict__ xw,
    const float* __restrict__ dtw, const float* __restrict__ dtb,
    float* __restrict__ ws) {
  int l0 = blockIdx.x * TT;
  int by = blockIdx.y; int b = by >> 2; int k = by & 3;
  int t = threadIdx.x;
  __shared__ float xv[128][9];
  __shared__ float pr[36][TT];
#pragma unroll
  for (int i = 0; i < TT; ++i) {
    int sp = spmap(k, l0 + i);
    xv[t][i] = ws[OX1S + ((size_t)(b * Ll) + sp) * 128 + t];
  }
  __syncthreads();
  if (t < 36) {
    float s[TT];
#pragma unroll
    for (int i = 0; i < TT; ++i) s[i] = 0.f;
    const float* wp = xw + (size_t)(k * 36 + t) * 128;
    for (int d = 0; d < 128; ++d) {
      float w = wp[d];
      const float* xc = &xv[d][0];
#pragma unroll
      for (int i = 0; i < TT; ++i) s[i] += xc[i] * w;
    }
#pragma unroll
    for (int i = 0; i < TT; ++i) pr[t][i] = s[i];
  }
  __syncthreads();
  {
    int d = t;
    const float* wp = dtw + (size_t)(k * 128 + d) * 4;
    float w0 = wp[0], w1 = wp[1], w2 = wp[2], w3 = wp[3];
    float bb = dtb[k * 128 + d];
#pragma unroll
    for (int i = 0; i < TT; ++i) {
      float v = pr[0][i] * w0 + pr[1][i] * w1 + pr[2][i] * w2 + pr[3][i] * w3 + bb;
      ws[ODT2 + ((size_t)(by * Ll + l0 + i)) * 128 + d] = softplusf(v);
    }
  }
  if (t < 16) {
#pragma unroll
    for (int i = 0; i < TT; ++i)
      ws[OBS2 + ((size_t)(by * Ll + l0 + i)) * 16 + t] = pr[4 + t][i];
  } else if (t < 32) {
#pragma unroll
    for (int i = 0; i < TT; ++i)
      ws[OCS2 + ((size_t)(by * Ll + l0 + i)) * 16 + (t - 16)] = pr[20 + (t - 16)][i];
  }
}

// ============ 7a. scan phase A (register-prefetch) ============
__global__ __launch_bounds__(256) void k_scanA(const float* __restrict__ alog,
                                               float* __restrict__ ws) {
  int c = blockIdx.x;
  int bk = blockIdx.y;
  int b = bk >> 2, k = bk & 3;
  int t = threadIdx.x;
  int n = t & 15, dg = t >> 4;
  __shared__ float dt_s[128], x_s[128], Bs_s[16];
  float A_r[8], ap[8], bc[8];
#pragma unroll
  for (int i = 0; i < 8; ++i) {
    int d = dg * 8 + i;
    A_r[i] = -__expf(alog[(size_t)((k * 128 + d) * 16) + n]);
    ap[i] = 1.f; bc[i] = 0.f;
  }
  const float* dtp = ws + ODT2 + ((size_t)bk * Ll) * 128;
  const float* bsp = ws + OBS2 + ((size_t)bk * Ll) * 16;
  const float* xb = ws + OX1S + (size_t)b * Ll * 128;
  float r_a = 0.f, r_Bs = 0.f;
  {
    int l = c * SCH;
    int sp = spmap(k, l);
    if (t < 128) r_a = dtp[(size_t)l * 128 + t];
    else r_a = xb[(size_t)sp * 128 + (t - 128)];
    if (t < 16) r_Bs = bsp[(size_t)l * 16 + t];
  }
  for (int ll = 0; ll < SCH; ++ll) {
    __syncthreads();
    if (t < 128) dt_s[t] = r_a;
    else x_s[t - 128] = r_a;
    if (t < 16) Bs_s[t] = r_Bs;
    __syncthreads();
    if (ll + 1 < SCH) {
      int l2 = c * SCH + ll + 1;
      int sp2 = spmap(k, l2);
      if (t < 128) r_a = dtp[(size_t)l2 * 128 + t];
      else r_a = xb[(size_t)sp2 * 128 + (t - 128)];
      if (t < 16) r_Bs = bsp[(size_t)l2 * 16 + t];
    }
    float Bv = Bs_s[n];
#pragma unroll
    for (int i = 0; i < 8; ++i) {
      int d = dg * 8 + i;
      float dtv = dt_s[d];
      float a = __expf(dtv * A_r[i]);
      bc[i] = bc[i] * a + dtv * x_s[d] * Bv;
      ap[i] *= a;
    }
  }
  float* csa = ws + OCSA + ((size_t)(bk * SNC + c) * 128) * 16;
  float* csb = ws + OCSB + ((size_t)(bk * SNC + c) * 128) * 16;
#pragma unroll
  for (int i = 0; i < 8; ++i) {
    int d = dg * 8 + i;
    csa[d * 16 + n] = ap[i];
    csb[d * 16 + n] = bc[i];
  }
}

// ============ 7b. scan phase B ============
__global__ __launch_bounds__(256) void k_scanB(float* __restrict__ ws) {
  int g = blockIdx.x * 256 + threadIdx.x;
  int bk = g >> 11;
  int dn = g & 2047;
  const float* csa = ws + OCSA;
  const float* csb = ws + OCSB;
  float* hst = ws + OHST;
  float h = 0.f;
  for (int c = 0; c < SNC; ++c) {
    size_t idx = (size_t)(bk * SNC + c) * 2048 + dn;
    hst[idx] = h;
    h = csa[idx] * h + csb[idx];
  }
}

// ============ 7c. scan phase C (register-prefetch) ============
__global__ __launch_bounds__(256) void k_scanC(const float* __restrict__ alog,
    const float* __restrict__ Dp, float* __restrict__ ws) {
  int c = blockIdx.x, bk = blockIdx.y;
  int b = bk >> 2, k = bk & 3;
  int t = threadIdx.x;
  int n = t & 15, dg = t >> 4;
  __shared__ float dt_s[128], x_s[128], Bs_s[16], Cs_s[16];
  float A_r[8], h[8], Dv[8];
#pragma unroll
  for (int i = 0; i < 8; ++i) {
    int d = dg * 8 + i;
    A_r[i] = -__expf(alog[(size_t)((k * 128 + d) * 16) + n]);
    h[i] = ws[OHST + ((size_t)(bk * SNC + c) * 128 + d) * 16 + n];
    Dv[i] = Dp[k * 128 + d];
  }
  const float* dtp = ws + ODT2 + ((size_t)bk * Ll) * 128;
  const float* bsp = ws + OBS2 + ((size_t)bk * Ll) * 16;
  const float* csp = ws + OCS2 + ((size_t)bk * Ll) * 16;
  const float* xb = ws + OX1S + (size_t)b * Ll * 128;
  float* yp = ws + OYS2 + ((size_t)bk * Ll) * 128;
  float r_a = 0.f, r_bc = 0.f;
  {
    int l = c * SCH;
    int sp = spmap(k, l);
    if (t < 128) r_a = dtp[(size_t)l * 128 + t];
    else r_a = xb[(size_t)sp * 128 + (t - 128)];
    if (t < 16) r_bc = bsp[(size_t)l * 16 + t];
    else if (t < 32) r_bc = csp[(size_t)l * 16 + (t - 16)];
  }
  for (int ll = 0; ll < SCH; ++ll) {
    __syncthreads();
    if (t < 128) dt_s[t] = r_a;
    else x_s[t - 128] = r_a;
    if (t < 16) Bs_s[t] = r_bc;
    else if (t < 32) Cs_s[t - 16] = r_bc;
    __syncthreads();
    if (ll + 1 < SCH) {
      int l2 = c * SCH + ll + 1;
      int sp2 = spmap(k, l2);
      if (t < 128) r_a = dtp[(size_t)l2 * 128 + t];
      else r_a = xb[(size_t)sp2 * 128 + (t - 128)];
      if (t < 16) r_bc = bsp[(size_t)l2 * 16 + t];
      else if (t < 32) r_bc = csp[(size_t)l2 * 16 + (t - 16)];
    }
    int l = c * SCH + ll;
    float Bv = Bs_s[n], Cv = Cs_s[n];
    float yacc[8];
#pragma unroll
    for (int i = 0; i < 8; ++i) {
      int d = dg * 8 + i;
      float dtv = dt_s[d];
      float a = __expf(dtv * A_r[i]);
      h[i] = h[i] * a + dtv * x_s[d] * Bv;
      yacc[i] = h[i] * Cv;
    }
#pragma unroll
    for (int i = 0; i < 8; ++i) {
      float yv = yacc[i];
      yv += __shfl_xor(yv, 1, 64);
      yv += __shfl_xor(yv, 2, 64);
      yv += __shfl_xor(yv, 4, 64);
      yv += __shfl_xor(yv, 8, 64);
      yacc[i] = yv;
    }
    if (n == 0) {
#pragma unroll
      for (int i = 0; i < 8; ++i) {
        int d = dg * 8 + i;
        yp[(size_t)l * 128 + d] = yacc[i] + Dv[i] * x_s[d];
      }
    }
  }
}

// ============ 8+9+10. comb + LN + gate + x2 + LN + FFN conv1 (fused, 8 tok) ============
__global__ __launch_bounds__(256) void k_combffn1(const float* __restrict__ enc,
    const float* __restrict__ nw, const float* __restrict__ nb,
    const float* __restrict__ snr, const float* __restrict__ ow,
    const float* __restrict__ lw, const float* __restrict__ lb,
    const float* __restrict__ w1, float* __restrict__ ws) {
  int l0 = blockIdx.x * TT, b = blockIdx.y, t = threadIdx.x;
  __shared__ float yr[128][9];
  __shared__ float redm[2][TT], redq[2][TT];
  __shared__ float part[2][TT][64];
  __shared__ float xn_s[64][9];
  int lane = t & 63, wid = (t >> 6) & 1;
  float v[TT], m[TT];
  // --- comb phase: gather 4 scan dirs ---
  if (t < 128) {
    int d = t;
    const float* ysb = ws + OYS2;
#pragma unroll
    for (int i = 0; i < TT; ++i) {
      int l = l0 + i;
      int hh = l / 48, wwp = l % 48;
      int lT = wwp * 48 + hh;
      v[i] = ysb[((size_t)(b * 4 + 0) * Ll + l) * 128 + d] +
             ysb[((size_t)(b * 4 + 2) * Ll + (2303 - l)) * 128 + d] +
             ysb[((size_t)(b * 4 + 1) * Ll + lT) * 128 + d] +
             ysb[((size_t)(b * 4 + 3) * Ll + (2303 - lT)) * 128 + d];
    }
    float s[TT];
#pragma unroll
    for (int i = 0; i < TT; ++i) s[i] = v[i];
#pragma unroll
    for (int o = 32; o >= 1; o >>= 1)
#pragma unroll
      for (int i = 0; i < TT; ++i) s[i] += __shfl_xor(s[i], o, 64);
    if (lane == 0) {
#pragma unroll
      for (int i = 0; i < TT; ++i) redm[wid][i] = s[i];
    }
  }
  __syncthreads();
  if (t < 128) {
    float q[TT];
#pragma unroll
    for (int i = 0; i < TT; ++i) {
      m[i] = (redm[0][i] + redm[1][i]) * (1.f / 128.f);
      float dv = v[i] - m[i];
      q[i] = dv * dv;
    }
#pragma unroll
    for (int o = 32; o >= 1; o >>= 1)
#pragma unroll
      for (int i = 0; i < TT; ++i) q[i] += __shfl_xor(q[i], o, 64);
    if (lane == 0) {
#pragma unroll
      for (int i = 0; i < TT; ++i) redq[wid][i] = q[i];
    }
  }
  __syncthreads();
  if (t < 128) {
    int d = t;
    float nwv = nw[d], nbv = nb[d];
#pragma unroll
    for (int i = 0; i < TT; ++i) {
      int l = l0 + i;
      float var = (redq[0][i] + redq[1][i]) * (1.f / 128.f);
      float y = (v[i] - m[i]) * rsqrtf(var + 1e-5f) * nwv + nbv;
      float zv = ws[OZ + ((size_t)(b * Ll + l)) * 128 + d];
      y *= siluf(zv);
      y *= snr[b * Ll + l];
      yr[d][i] = y;
    }
  }
  __syncthreads();
  // --- out-proj GEMM (128 -> 64) ---
  if (t < 128) {
    int col = t & 63, seg = t >> 6;
    float acc[TT];
#pragma unroll
    for (int i = 0; i < TT; ++i) acc[i] = 0.f;
    const float* ows = ow + (size_t)(seg * 64) * 64 + col;
    for (int c = 0; c < 64; ++c) {
      float w = ows[c * 64];
      const float* yc = &yr[seg * 64 + c][0];
#pragma unroll
      for (int i = 0; i < TT; ++i) acc[i] += yc[i] * w;
    }
#pragma unroll
    for (int i = 0; i < TT; ++i) part[seg][i][col] = acc[i];
  }
  __syncthreads();
  // --- residual + LN(64) ---
  if (t < 64) {
    float lwv = lw[t], lbv = lb[t];
#pragma unroll
    for (int i = 0; i < TT; ++i) {
      float a = part[0][i][t] + part[1][i][t];
      a += enc[(size_t)b * Cc * Ll + (size_t)t * Ll + l0 + i];
      ws[OX2 + ((size_t)(b * Ll + l0 + i)) * 64 + t] = a;
      float s = a;
#pragma unroll
      for (int o = 32; o >= 1; o >>= 1) s += __shfl_xor(s, o, 64);
      float mm = s * (1.f / 64.f);
      float dd2 = a - mm;
      float vs = dd2 * dd2;
#pragma unroll
      for (int o = 32; o >= 1; o >>= 1) vs += __shfl_xor(vs, o, 64);
      xn_s[t][i] = dd2 * rsqrtf(vs * (1.f / 64.f) + 1e-5f) * lwv + lbv;
    }
  }
  __syncthreads();
  // --- FFN conv1 (64 -> 256) + gelu ---
  {
    float acc2[TT];
#pragma unroll
    for (int i = 0; i < TT; ++i) acc2[i] = 0.f;
    const float* wp = w1 + (size_t)t * 64;
    for (int c = 0; c < 64; ++c) {
      float w = wp[c];
      const float* xc = &xn_s[c][0];
#pragma unroll
      for (int i = 0; i < TT; ++i) acc2[i] += xc[i] * w;
    }
#pragma unroll
    for (int i = 0; i < TT; ++i)
      ws[OH1A + ((size_t)(b * Ll + l0 + i)) * 256 + t] = geluf(acc2[i]);
  }
}

// ============ 11. FFN depthwise 3x3 + gelu, 8 tokens/block ============
__global__ __launch_bounds__(256) void k_ffndw(const float* __restrict__ dww,
                                               float* __restrict__ ws) {
  int l0 = blockIdx.x * TT, b = blockIdx.y, t = threadIdx.x;
  int h = l0 / 48, w0 = l0 % 48;
  __shared__ float tile[3][10][256];
  for (int idx = t; idx < 7680; idx += 256) {
    int r = idx / 2560, rem = idx % 2560;
    int col = rem >> 8, ch = rem & 255;
    int hh = h + r - 1, wx = w0 + col - 1;
    float v = 0.f;
    if (hh >= 0 && hh < 48 && wx >= 0 && wx < 48)
      v = ws[OH1A + ((size_t)(b * Ll + hh * 48 + wx)) * 256 + ch];
    tile[r][col][ch] = v;
  }
  __syncthreads();
  float dwr[9];
#pragma unroll
  for (int j = 0; j < 9; ++j) dwr[j] = dww[t * 9 + j];
#pragma unroll
  for (int i = 0; i < TT; ++i) {
    float acc = 0.f;
#pragma unroll
    for (int kh = 0; kh < 3; ++kh)
#pragma unroll
      for (int kw = 0; kw < 3; ++kw)
        acc += tile[kh][i + kw][t] * dwr[kh * 3 + kw];
    ws[OH1B + ((size_t)(b * Ll + l0 + i)) * 256 + t] = geluf(acc);
  }
}

// ============ 12. FFN conv2 1x1 + residual + transposed out, 8 tokens/block ============
__global__ __launch_bounds__(256) void k_ffn2(const float* __restrict__ w2,
                                              float* __restrict__ ws,
                                              float* __restrict__ out) {
  int l0 = blockIdx.x * TT, b = blockIdx.y, t = threadIdx.x;
  __shared__ float hr[256][9];
  __shared__ float part[4][TT][64];
  const float* hp = ws + OH1B + ((size_t)(b * Ll + l0)) * 256;
#pragma unroll
  for (int i = 0; i < TT; ++i) hr[t][i] = hp[(size_t)i * 256 + t];
  __syncthreads();
  int col = t & 63, seg = t >> 6;
  {
    float acc[TT];
#pragma unroll
    for (int i = 0; i < TT; ++i) acc[i] = 0.f;
    const float* wp = w2 + (size_t)col * 256 + seg * 64;
    for (int c = 0; c < 64; ++c) {
      float w = wp[c];
      const float* hc = &hr[seg * 64 + c][0];
#pragma unroll
      for (int i = 0; i < TT; ++i) acc[i] += hc[i] * w;
    }
#pragma unroll
    for (int i = 0; i < TT; ++i) part[seg][i][col] = acc[i];
  }
  __syncthreads();
  if (t < 64) {
    float av[TT];
#pragma unroll
    for (int i = 0; i < TT; ++i) {
      float a = part[0][i][t] + part[1][i][t] + part[2][i][t] + part[3][i][t];
      av[i] = a + ws[OX2 + ((size_t)(b * Ll + l0 + i)) * 64 + t];
    }
    float* opx = out + ((size_t)(b * 64 + t)) * 2304 + l0;
    *(float4*)opx = make_float4(av[0], av[1], av[2], av[3]);
    *((float4*)opx + 1) = make_float4(av[4], av[5], av[6], av[7]);
  }
}

extern "C" void kernel_launch(void* const* d_in, const int* in_sizes, int n_in,
                              void* d_out, int out_size, void* d_ws, size_t ws_size,
                              hipStream_t stream) {
  (void)in_sizes; (void)n_in; (void)out_size;
  const float* enc  = (const float*)d_in[0];
  const float* snr  = (const float*)d_in[1];
  const float* wq   = (const float*)d_in[2];
  const float* wk   = (const float*)d_in[3];
  const float* wv   = (const float*)d_in[4];
  const float* fc   = (const float*)d_in[5];
  const float* alnw = (const float*)d_in[6];
  const float* alnb = (const float*)d_in[7];
  const float* ssin = (const float*)d_in[8];
  const float* cw   = (const float*)d_in[9];
  const float* cb   = (const float*)d_in[10];
  const float* xw   = (const float*)d_in[11];
  const float* dtw  = (const float*)d_in[12];
  const float* dtb  = (const float*)d_in[13];
  const float* alog = (const float*)d_in[14];
  const float* Dp   = (const float*)d_in[15];
  const float* nw   = (const float*)d_in[16];
  const float* nb   = (const float*)d_in[17];
  const float* ow   = (const float*)d_in[18];
  const float* flnw = (const float*)d_in[19];
  const float* flnb = (const float*)d_in[20];
  const float* w1   = (const float*)d_in[21];
  const float* dww  = (const float*)d_in[22];
  const float* w2   = (const float*)d_in[23];
  float* ws = (float*)d_ws;
  float* out = (float*)d_out;

  if (ws_size < (size_t)WS_NEED_FLOATS * 4) {
    hipLaunchKernelGGL(k_code, dim3(1), dim3(64), 0, stream, out);
    return;
  }

  hipLaunchKernelGGL(k_qkv, dim3(Ll / TT, Bq), dim3(256), 0, stream, enc, wq, wk, wv, ws);
  hipLaunchKernelGGL(k_vt, dim3(Ll / 64, Bq * NHh), dim3(256), 0, stream, ws);
  hipLaunchKernelGGL(k_attn, dim3(Ll / 64, Bq * NHh), dim3(256), 0, stream, snr, ws);
  hipLaunchKernelGGL(k_oprojxz, dim3(Ll / TT, Bq), dim3(256), 0, stream, enc, fc, alnw, alnb, ssin, ws);
  hipLaunchKernelGGL(k_conv, dim3(Ll / TT, Bq), dim3(256), 0, stream, cw, cb, ws);
  hipLaunchKernelGGL(k_xdbl, dim3(Ll / TT, Bq * 4), dim3(128), 0, stream, xw, dtw, dtb, ws);
  hipLaunchKernelGGL(k_scanA, dim3(SNC, Bq * 4), dim3(256), 0, stream, alog, ws);
  hipLaunchKernelGGL(k_scanB, dim3(64), dim3(256), 0, stream, ws);
  hipLaunchKernelGGL(k_scanC, dim3(SNC, Bq * 4), dim3(256), 0, stream, alog, Dp, ws);
  hipLaunchKernelGGL(k_combffn1, dim3(Ll / TT, Bq), dim3(256), 0, stream, enc, nw, nb, snr, ow, flnw, flnb, w1, ws);
  hipLaunchKernelGGL(k_ffndw, dim3(Ll / TT, Bq), dim3(256), 0, stream, dww, ws);
  hipLaunchKernelGGL(k_ffn2, dim3(Ll / TT, Bq), dim3(256), 0, stream, w2, ws, out);
}